// Round 1
// 388.859 us; speedup vs baseline: 1.0461x; 1.0461x over previous
//
#include <hip/hip_runtime.h>
#include <math.h>

#define SLOPE 0.01f
#define BKS   256        // dests per bucket (R12: 1024 -> 98 blocks was launch-width-bound)
#define BSH2  8          // log2(BKS)
#define NBKMAX 512       // max coarse buckets (N <= 131072)
#define BCAP  10240      // fixed bucket capacity (mean 8192 + 22 sigma)

typedef short  bf16x8 __attribute__((ext_vector_type(8)));
typedef float  f32x4  __attribute__((ext_vector_type(4)));

__device__ __forceinline__ float lrelu(float v) { return v >= 0.f ? v : SLOPE * v; }

__device__ __forceinline__ unsigned short f2bf(float v) {
    unsigned u = __float_as_uint(v);
    return (unsigned short)((u + 0x7FFFu + ((u >> 16) & 1u)) >> 16);   // RNE
}
__device__ __forceinline__ float bf2f(unsigned short b) {
    return __uint_as_float(((unsigned)b) << 16);
}

// ---------------------------------------------------------------------------
// GRU step (h0=0), regenerate GCN weights, fold Wout/bout, split W2 to bf16
// hi/lo (for MFMA stage2), and init the fixed-capacity bucket cursors.
// ---------------------------------------------------------------------------
__global__ void prep_k(const float* __restrict__ m1, const float* __restrict__ Wih1,
                       const float* __restrict__ bih1, const float* __restrict__ bhh1,
                       const float* __restrict__ m2, const float* __restrict__ Wih2,
                       const float* __restrict__ bih2, const float* __restrict__ bhh2,
                       const float* __restrict__ wtW1, const float* __restrict__ wtb1,
                       const float* __restrict__ wtW2, const float* __restrict__ wtb2,
                       const float* __restrict__ Wout, const float* __restrict__ bout,
                       const float* __restrict__ W2,
                       float* __restrict__ Wn1, float* __restrict__ Wn2,
                       float* __restrict__ wsum, float* __restrict__ bsum,
                       unsigned short* __restrict__ W2bh, unsigned short* __restrict__ W2bl,
                       int* __restrict__ bfill, int NBK) {
    __shared__ float nm[32];   // new_mem1 [0..15], new_mem2 [16..31]
    int t = threadIdx.x;
    if (t < 32) {
        int L = t >> 4, j = t & 15;
        const float* m   = L ? m2   : m1;
        const float* Wih = L ? Wih2 : Wih1;
        const float* bih = L ? bih2 : bih1;
        const float* bhh = L ? bhh2 : bhh1;
        float gr = bih[j], gz = bih[16 + j], gn = bih[32 + j];
        for (int k = 0; k < 16; ++k) {
            float mk = m[k];
            gr += Wih[j * 16 + k] * mk;
            gz += Wih[(16 + j) * 16 + k] * mk;
            gn += Wih[(32 + j) * 16 + k] * mk;
        }
        float r = 1.f / (1.f + expf(-(gr + bhh[j])));
        float z = 1.f / (1.f + expf(-(gz + bhh[16 + j])));
        float n = tanhf(gn + r * bhh[32 + j]);
        nm[t] = (1.f - z) * n;          // + z*h, h==0
    }
    __syncthreads();
    float s1 = wtb1[t], s2 = wtb2[t];
    for (int k = 0; k < 16; ++k) {
        s1 += wtW1[t * 16 + k] * nm[k];
        s2 += wtW2[t * 16 + k] * nm[16 + k];
    }
    Wn1[t] = s1;
    Wn2[t] = s2;
    // W2 [16][256] -> bf16 hi/lo split (row-major, MFMA B-fragment friendly)
    for (int i = t; i < 4096; i += 256) {
        float v = W2[i];
        unsigned short h = f2bf(v);
        W2bh[i] = h;
        W2bl[i] = f2bf(v - bf2f(h));
    }
    if (t < 16) wsum[t] = Wout[t] + Wout[16 + t];
    if (t == 0) bsum[0] = bout[0] + bout[1];
    for (int i = t; i < NBK; i += 256) bfill[i] = i * BCAP;
}

// Split W1 into bf16 hi/lo pair (for split-bf16 MFMA GEMM). 32768 elems.
__global__ void wsplit_k(const float* __restrict__ W1,
                         unsigned short* __restrict__ W1h,
                         unsigned short* __restrict__ W1l) {
    int i = blockIdx.x * 256 + threadIdx.x;
    float v = W1[i];
    unsigned short h = f2bf(v);
    W1h[i] = h;
    W1l[i] = f2bf(v - bf2f(h));
}

// ---------------------------------------------------------------------------
// CSR build: bscat (fixed-base buckets) -> cscan (1 block) -> bproc.
// ---------------------------------------------------------------------------
__global__ void bscat_k(const int* __restrict__ row, const int* __restrict__ col,
                        int* __restrict__ bfill, int2* __restrict__ stage,
                        int E, int NBK) {
    __shared__ int lcnt[NBKMAX];
    __shared__ int lbase[NBKMAX];
    int t = threadIdx.x;
    for (int i = t; i < NBK; i += 256) lcnt[i] = 0;
    __syncthreads();
    int base = blockIdx.x * 4096;
    int r[16], d[16], sl[16];
#pragma unroll
    for (int i = 0; i < 16; ++i) {
        int e = base + i * 256 + t;
        if (e < E) {
            r[i]  = row[e];
            d[i]  = col[e];
            sl[i] = atomicAdd(&lcnt[d[i] >> BSH2], 1);
        } else d[i] = -1;
    }
    __syncthreads();
    for (int i = t; i < NBK; i += 256)
        lbase[i] = lcnt[i] ? atomicAdd(bfill + i, lcnt[i]) : 0;
    __syncthreads();
#pragma unroll
    for (int i = 0; i < 16; ++i) {
        if (d[i] >= 0)
            stage[lbase[d[i] >> BSH2] + sl[i]] = make_int2(r[i], d[i]);
    }
}

// single block: counts from bfill, exclusive scan -> contiguous CSR bases
__global__ __launch_bounds__(512) void cscan_k(const int* __restrict__ bfill,
                                               int* __restrict__ bbase2,
                                               int* __restrict__ off,
                                               int NBK, int N, int E) {
    __shared__ int s[512];
    int t = threadIdx.x;
    int v = (t < NBK) ? (bfill[t] - t * BCAP) : 0;
    s[t] = v;
    __syncthreads();
    for (int d = 1; d < 512; d <<= 1) {
        int u = (t >= d) ? s[t - d] : 0;
        __syncthreads();
        s[t] += u;
        __syncthreads();
    }
    if (t < NBK) bbase2[t] = s[t] - v;
    if (t == 0) { bbase2[NBK] = E; off[N] = E; }
}

// one block per 256-dest bucket: LDS hist (1 counter/thread) -> 256-scan ->
// off/dis -> in-window scatter (~32 KB window, L2-resident). LDS atomics only.
__global__ void bproc_k(const int2* __restrict__ stage, const int* __restrict__ bbase2,
                        int* __restrict__ off, float* __restrict__ dis,
                        int* __restrict__ srcs, int N) {
    __shared__ int lh[BKS];    // counts, then cursors
    __shared__ int ssc[BKS];   // scan
    const int b  = blockIdx.x;
    const int t  = threadIdx.x;
    const int sb = b * BCAP;                     // stage read base
    const int e0 = bbase2[b];
    const int cnt = bbase2[b + 1] - e0;
    lh[t] = 0;
    __syncthreads();
    for (int i = t; i < cnt; i += 256) {
        int2 v = stage[sb + i];
        atomicAdd(&lh[v.y & (BKS - 1)], 1);
    }
    __syncthreads();
    int c = lh[t];
    ssc[t] = c;
    __syncthreads();
    for (int d = 1; d < 256; d <<= 1) {
        int u = (t >= d) ? ssc[t - d] : 0;
        __syncthreads();
        ssc[t] += u;
        __syncthreads();
    }
    int ex = ssc[t] - c;       // exclusive offset within bucket
    {
        int node = b * BKS + t;
        if (node < N) {
            off[node] = e0 + ex;
            dis[node] = rsqrtf((float)(c + 1));   // in-degree + self-loop
        }
    }
    __syncthreads();
    lh[t] = ex;                // cursors
    __syncthreads();
    for (int i = t; i < cnt; i += 256) {
        int2 w = stage[sb + i];
        int pos = e0 + atomicAdd(&lh[w.y & (BKS - 1)], 1);
        srcs[pos] = w.x;
    }
}

// ---------------------------------------------------------------------------
// Fused MLP v6: all-MFMA, latency-chain free.
//   P0: x loads + W1 B-frag preload (VGPR) + bf16 hi/lo staging
//   P1: GEMM1 (256-wide) split-bf16 MFMA, B register-resident
//   P2: W2 B-frag preload + h1 -> bf16 hi/lo LDS (overlay x tile)
//   P3: GEMM2 (64x16x256) split-bf16 MFMA, K halved across wave pairs
//   P4: partial combine + b2/lrelu + Wn1 (16x16) + dis scale + store
// No scalar-mem loads inside any inner loop (was the lgkmcnt serializer).
// ---------------------------------------------------------------------------
__global__ __launch_bounds__(512, 4) void mlp_k(
        const float* __restrict__ x,
        const unsigned short* __restrict__ W1h,
        const unsigned short* __restrict__ W1l,
        const float* __restrict__ b1,
        const unsigned short* __restrict__ W2bh,
        const unsigned short* __restrict__ W2bl,
        const float* __restrict__ b2,
        const float* __restrict__ Wn1,
        const float* __restrict__ dis,
        float* __restrict__ xl, int N) {
    __shared__ float sbuf[19456];                    // 77824 B -> 2 blocks/CU
    unsigned short* xh  = (unsigned short*)sbuf;     // x  [64][136] bf16 hi
    unsigned short* xlo = xh + 8704;                 // x  [64][136] bf16 lo
    unsigned short* h1h = (unsigned short*)sbuf;     // h1 [64][264] bf16 hi (overlay)
    unsigned short* h1l = h1h + 16896;               // h1 [64][264] bf16 lo
    float*          h2p = sbuf + 16896;              // [2][64][20] f32 partials

    const int t      = threadIdx.x;
    const int nl     = t & 63;
    const int q      = __builtin_amdgcn_readfirstlane(t >> 6);  // wave 0..7
    const int lane15 = t & 15;
    const int quad   = (t & 63) >> 4;
    const int node   = blockIdx.x * 64 + nl;
    const bool valid = node < N;

    // ---- P0a: issue x loads (wave q stages k in [q*16, q*16+16)) ----
    float4 xv[4];
    if (valid) {
        const float4* xr = (const float4*)(x + (size_t)node * 128) + q * 4;
#pragma unroll
        for (int kk = 0; kk < 4; ++kk) xv[kk] = xr[kk];
    }

    // ---- P0b: preload W1 B-fragments (16 x b128, L2-hot; latency hides
    //           under x-load wait + conversion + barrier) ----
    bf16x8 w1hf[2][4], w1lf[2][4];                   // [nt][ks]
#pragma unroll
    for (int nt = 0; nt < 2; ++nt)
#pragma unroll
        for (int ks = 0; ks < 4; ++ks) {
            size_t wo = (size_t)(q * 32 + nt * 16 + lane15) * 128 + ks * 32 + quad * 8;
            w1hf[nt][ks] = *(const bf16x8*)(W1h + wo);
            w1lf[nt][ks] = *(const bf16x8*)(W1l + wo);
        }

    // ---- P0c: convert + stage x ----
    {
        unsigned* xh32 = (unsigned*)xh;
        unsigned* xl32 = (unsigned*)xlo;
        int base = nl * 68 + q * 8;                  // uint index (row stride 68)
        if (valid) {
#pragma unroll
            for (int kk = 0; kk < 4; ++kk) {
                float4 v = xv[kk];
                unsigned short hx = f2bf(v.x), hy = f2bf(v.y);
                unsigned short hz = f2bf(v.z), hw = f2bf(v.w);
                unsigned short lx = f2bf(v.x - bf2f(hx)), ly = f2bf(v.y - bf2f(hy));
                unsigned short lz = f2bf(v.z - bf2f(hz)), lw = f2bf(v.w - bf2f(hw));
                *(uint2*)(xh32 + base + kk * 2) =
                    make_uint2((unsigned)hx | ((unsigned)hy << 16),
                               (unsigned)hz | ((unsigned)hw << 16));
                *(uint2*)(xl32 + base + kk * 2) =
                    make_uint2((unsigned)lx | ((unsigned)ly << 16),
                               (unsigned)lz | ((unsigned)lw << 16));
            }
        } else {
#pragma unroll
            for (int kk = 0; kk < 4; ++kk) {
                *(uint2*)(xh32 + base + kk * 2) = make_uint2(0u, 0u);
                *(uint2*)(xl32 + base + kk * 2) = make_uint2(0u, 0u);
            }
        }
    }
    __syncthreads();

    // ---- P1: GEMM1, wave q owns hu in [q*32, q*32+32); B in registers ----
    f32x4 acc[4][2];
#pragma unroll
    for (int mt = 0; mt < 4; ++mt)
#pragma unroll
        for (int nt = 0; nt < 2; ++nt)
            acc[mt][nt] = (f32x4){0.f, 0.f, 0.f, 0.f};

#pragma unroll
    for (int ks = 0; ks < 4; ++ks) {
        const int koff = ks * 32 + quad * 8;
#pragma unroll
        for (int mt = 0; mt < 4; ++mt) {
            bf16x8 ah = *(const bf16x8*)(xh  + (16 * mt + lane15) * 136 + koff);
            bf16x8 al = *(const bf16x8*)(xlo + (16 * mt + lane15) * 136 + koff);
#pragma unroll
            for (int nt = 0; nt < 2; ++nt) {
                acc[mt][nt] = __builtin_amdgcn_mfma_f32_16x16x32_bf16(ah, w1hf[nt][ks], acc[mt][nt], 0, 0, 0);
                acc[mt][nt] = __builtin_amdgcn_mfma_f32_16x16x32_bf16(ah, w1lf[nt][ks], acc[mt][nt], 0, 0, 0);
                acc[mt][nt] = __builtin_amdgcn_mfma_f32_16x16x32_bf16(al, w1hf[nt][ks], acc[mt][nt], 0, 0, 0);
            }
        }
    }
    __syncthreads();   // x tile dead; safe to overlay h1

    // ---- P2a: preload W2 B-fragments for this wave's K-half ----
    const int kh  = q >> 2;        // K-half for stage2
    const int mt2 = q & 3;         // m-tile for stage2
    bf16x8 w2hf[4], w2lf[4];
#pragma unroll
    for (int ks2 = 0; ks2 < 4; ++ks2) {
        int wo = lane15 * 256 + (kh * 4 + ks2) * 32 + quad * 8;
        w2hf[ks2] = *(const bf16x8*)(W2bh + wo);
        w2lf[ks2] = *(const bf16x8*)(W2bl + wo);
    }

    // ---- P2b: epilogue GEMM1 -> h1 bf16 hi/lo in LDS ----
#pragma unroll
    for (int nt = 0; nt < 2; ++nt) {
        int hu = q * 32 + nt * 16 + lane15;
        float bb = b1[hu];
#pragma unroll
        for (int mt = 0; mt < 4; ++mt) {
            int row0 = 16 * mt + quad * 4;
#pragma unroll
            for (int r = 0; r < 4; ++r) {
                float v = lrelu(acc[mt][nt][r] + bb);
                unsigned short h = f2bf(v);
                h1h[(row0 + r) * 264 + hu] = h;
                h1l[(row0 + r) * 264 + hu] = f2bf(v - bf2f(h));
            }
        }
    }
    __syncthreads();

    // ---- P3: GEMM2 partial (wave q: rows 16*mt2.., K-half kh) ----
    f32x4 a2 = (f32x4){0.f, 0.f, 0.f, 0.f};
#pragma unroll
    for (int ks2 = 0; ks2 < 4; ++ks2) {
        const int koff = (kh * 4 + ks2) * 32 + quad * 8;
        bf16x8 ah = *(const bf16x8*)(h1h + (16 * mt2 + lane15) * 264 + koff);
        bf16x8 al = *(const bf16x8*)(h1l + (16 * mt2 + lane15) * 264 + koff);
        a2 = __builtin_amdgcn_mfma_f32_16x16x32_bf16(ah, w2hf[ks2], a2, 0, 0, 0);
        a2 = __builtin_amdgcn_mfma_f32_16x16x32_bf16(ah, w2lf[ks2], a2, 0, 0, 0);
        a2 = __builtin_amdgcn_mfma_f32_16x16x32_bf16(al, w2hf[ks2], a2, 0, 0, 0);
    }
    {
        // h2p[kh][row][j], row = 16*mt2 + quad*4 + r, j = lane15, stride 20
        float* dst = h2p + kh * 1280 + (16 * mt2 + quad * 4) * 20 + lane15;
        dst[0] = a2[0]; dst[20] = a2[1]; dst[40] = a2[2]; dst[60] = a2[3];
    }
    __syncthreads();

    // ---- P4: combine partials, b2 + lrelu, Wn1 (16x16), dis scale, store ----
    {
        const f32x4* pa = (const f32x4*)(h2p + nl * 20);
        const f32x4* pb = (const f32x4*)(h2p + 1280 + nl * 20);
        f32x4 s[4];
#pragma unroll
        for (int i = 0; i < 4; ++i) s[i] = pa[i] + pb[i];
        float o0 = 0.f, o1 = 0.f;
        const float* wr0 = Wn1 + (2 * q) * 16;       // uniform -> s_load (one-shot)
        const float* wr1 = Wn1 + (2 * q + 1) * 16;
#pragma unroll
        for (int j = 0; j < 16; ++j) {
            float h = lrelu(s[j >> 2][j & 3] + b2[j]);
            o0 = fmaf(wr0[j], h, o0);
            o1 = fmaf(wr1[j], h, o1);
        }
        if (valid) {
            float d = dis[node];
            float2* xo = (float2*)(xl + (size_t)node * 16 + 2 * q);
            *xo = make_float2(d * o0, d * o1);
        }
    }
}

// ---------------------------------------------------------------------------
// Gather layer 1 (wave per node, 4-deep batched gathers — R11-proven)
// ---------------------------------------------------------------------------
__global__ void gather1_k(const int* __restrict__ off, const int* __restrict__ srcs,
                          const float* __restrict__ dis, const float* __restrict__ xin,
                          const float* __restrict__ bias, const float* __restrict__ Wn2,
                          float* __restrict__ xout, int N) {
    __shared__ float w[256];             // transposed: w[j*16+c] = Wn2[c*16+j]
    {
        int j = threadIdx.x >> 4, c = threadIdx.x & 15;
        w[threadIdx.x] = Wn2[c * 16 + j];
    }
    __syncthreads();
    int t = blockIdx.x * 256 + threadIdx.x;
    int n = t >> 6;
    if (n >= N) return;
    int lane = t & 63, sub = lane >> 4, c = lane & 15;
    float acc = (sub == 0) ? xin[(size_t)n * 16 + c] : 0.f;   // self term
    int e  = off[n] + sub;
    int e1 = off[n + 1];
    for (; e + 12 < e1; e += 16) {
        int s0 = srcs[e], s1 = srcs[e + 4], s2 = srcs[e + 8], s3 = srcs[e + 12];
        float v0 = xin[(size_t)s0 * 16 + c];
        float v1 = xin[(size_t)s1 * 16 + c];
        float v2 = xin[(size_t)s2 * 16 + c];
        float v3 = xin[(size_t)s3 * 16 + c];
        acc += (v0 + v1) + (v2 + v3);
    }
    for (; e < e1; e += 4)
        acc += xin[(size_t)srcs[e] * 16 + c];
    acc += __shfl_xor(acc, 16);
    acc += __shfl_xor(acc, 32);
    float d = dis[n];
    float h = lrelu(fmaf(d, acc, bias[c]));
    float o = 0.f;
#pragma unroll
    for (int j = 0; j < 16; ++j) o = fmaf(w[j * 16 + c], __shfl(h, j, 16), o);
    if (sub == 0) xout[(size_t)n * 16 + c] = d * o;
}

// ---------------------------------------------------------------------------
// Gather layer 2 + final projection (same 4-deep batching)
// ---------------------------------------------------------------------------
__global__ void gather2_k(const int* __restrict__ off, const int* __restrict__ srcs,
                          const float* __restrict__ dis, const float* __restrict__ xin,
                          const float* __restrict__ bias, const float* __restrict__ wsum,
                          const float* __restrict__ bsum, float* __restrict__ out, int N) {
    int t = blockIdx.x * 256 + threadIdx.x;
    int n = t >> 6;
    if (n >= N) return;
    int lane = t & 63, sub = lane >> 4, c = lane & 15;
    float acc = (sub == 0) ? xin[(size_t)n * 16 + c] : 0.f;
    int e  = off[n] + sub;
    int e1 = off[n + 1];
    for (; e + 12 < e1; e += 16) {
        int s0 = srcs[e], s1 = srcs[e + 4], s2 = srcs[e + 8], s3 = srcs[e + 12];
        float v0 = xin[(size_t)s0 * 16 + c];
        float v1 = xin[(size_t)s1 * 16 + c];
        float v2 = xin[(size_t)s2 * 16 + c];
        float v3 = xin[(size_t)s3 * 16 + c];
        acc += (v0 + v1) + (v2 + v3);
    }
    for (; e < e1; e += 4)
        acc += xin[(size_t)srcs[e] * 16 + c];
    acc += __shfl_xor(acc, 16);
    acc += __shfl_xor(acc, 32);
    float v = wsum[c] * lrelu(fmaf(dis[n], acc, bias[c]));
#pragma unroll
    for (int m = 1; m < 16; m <<= 1) v += __shfl_xor(v, m);
    if (lane == 0) out[n] = v + bsum[0];
}

// ---------------------------------------------------------------------------
extern "C" void kernel_launch(void* const* d_in, const int* in_sizes, int n_in,
                              void* d_out, int out_size, void* d_ws, size_t ws_size,
                              hipStream_t stream) {
    const float* x      = (const float*)d_in[0];
    const int*   edge   = (const int*)d_in[1];
    const float* W1     = (const float*)d_in[2];
    const float* b1     = (const float*)d_in[3];
    const float* W2     = (const float*)d_in[4];
    const float* b2     = (const float*)d_in[5];
    const float* mem1   = (const float*)d_in[6];
    const float* g1_Wih = (const float*)d_in[7];
    const float* g1_bih = (const float*)d_in[9];
    const float* g1_bhh = (const float*)d_in[10];
    const float* wt1_W  = (const float*)d_in[11];
    const float* wt1_b  = (const float*)d_in[12];
    const float* gcn1_b = (const float*)d_in[13];
    const float* mem2   = (const float*)d_in[14];
    const float* g2_Wih = (const float*)d_in[15];
    const float* g2_bih = (const float*)d_in[17];
    const float* g2_bhh = (const float*)d_in[18];
    const float* wt2_W  = (const float*)d_in[19];
    const float* wt2_b  = (const float*)d_in[20];
    const float* gcn2_b = (const float*)d_in[21];
    const float* Wout   = (const float*)d_in[22];
    const float* bout   = (const float*)d_in[23];
    float* out = (float*)d_out;

    const int N = in_sizes[0] / 128;
    const int E = in_sizes[1] / 2;
    const int* row = edge;
    const int* col = edge + E;

    const int NBK = (N + BKS - 1) >> BSH2;   // coarse buckets (391 @ N=100k)
    const int gM  = (N + 63) / 64;           // mlp blocks (64 nodes, 512 thr)
    const int gG  = (N * 64 + 255) / 256;    // gather blocks (wave per node)
    const int gB  = (E + 4095) / 4096;       // bscat blocks

    float* ws    = (float*)d_ws;
    float* bufA  = ws;                        // [N*16] xl1 (dis-scaled)
    float* bufB  = bufA + (size_t)N * 16;     // [N*16] xl2 (dis-scaled)
    float* dis   = bufB + (size_t)N * 16;     // [N]
    float* sm    = dis + N;                   // smalls
    float* Wn1   = sm;
    float* Wn2   = sm + 256;
    float* wsum  = sm + 512;
    float* bsum  = sm + 528;
    unsigned short* W2bh = (unsigned short*)(sm + 544);   // [16*256] bf16 hi (8 KB)
    unsigned short* W2bl = (unsigned short*)(sm + 2592);  // [16*256] bf16 lo (8 KB)
    unsigned short* W1h = (unsigned short*)(sm + 4640);   // [256*128] bf16 hi
    unsigned short* W1l = (unsigned short*)(sm + 21024);  // [256*128] bf16 lo
    int*   bfill = (int*)(sm + 37408);        // [NBKMAX]
    int*   bbase2= bfill + NBKMAX;            // [NBKMAX+1]
    int*   off   = bbase2 + NBKMAX + 1;       // [N+1]
    int*   srcs  = off + N + 1;               // [E]
    // stage: 16B-aligned int2[NBK*BCAP]
    size_t stoff = (size_t)(srcs + E - (int*)d_ws);
    stoff = (stoff + 3) & ~(size_t)3;
    int2*  stage = (int2*)((int*)d_ws + stoff);

    prep_k<<<1, 256, 0, stream>>>(mem1, g1_Wih, g1_bih, g1_bhh,
                                  mem2, g2_Wih, g2_bih, g2_bhh,
                                  wt1_W, wt1_b, wt2_W, wt2_b,
                                  Wout, bout, W2, Wn1, Wn2, wsum, bsum,
                                  W2bh, W2bl, bfill, NBK);
    wsplit_k<<<128, 256, 0, stream>>>(W1, W1h, W1l);
    bscat_k<<<gB, 256, 0, stream>>>(row, col, bfill, stage, E, NBK);
    cscan_k<<<1, 512, 0, stream>>>(bfill, bbase2, off, NBK, N, E);
    bproc_k<<<NBK, 256, 0, stream>>>(stage, bbase2, off, dis, srcs, N);
    mlp_k<<<gM, 512, 0, stream>>>(x, W1h, W1l, b1, W2bh, W2bl, b2, Wn1, dis, bufA, N);
    gather1_k<<<gG, 256, 0, stream>>>(off, srcs, dis, bufA, gcn1_b, Wn2, bufB, N);
    gather2_k<<<gG, 256, 0, stream>>>(off, srcs, dis, bufB, gcn2_b, wsum, bsum, out, N);
}

// Round 2
// 375.483 us; speedup vs baseline: 1.0834x; 1.0356x over previous
//
#include <hip/hip_runtime.h>
#include <math.h>

#define SLOPE 0.01f
#define BKS   256        // dests per bucket (R12: 1024 -> 98 blocks was launch-width-bound)
#define BSH2  8          // log2(BKS)
#define NBKMAX 512       // max coarse buckets (N <= 131072)
#define BCAP  10240      // fixed bucket capacity (mean 8192 + 22 sigma)

typedef short  bf16x8 __attribute__((ext_vector_type(8)));
typedef float  f32x4  __attribute__((ext_vector_type(4)));

__device__ __forceinline__ float lrelu(float v) { return v >= 0.f ? v : SLOPE * v; }

__device__ __forceinline__ unsigned short f2bf(float v) {
    unsigned u = __float_as_uint(v);
    return (unsigned short)((u + 0x7FFFu + ((u >> 16) & 1u)) >> 16);   // RNE
}
__device__ __forceinline__ float bf2f(unsigned short b) {
    return __uint_as_float(((unsigned)b) << 16);
}

// ---------------------------------------------------------------------------
// GRU step (h0=0), regenerate GCN weights, fold Wout/bout, split W2 to bf16
// hi/lo (for MFMA stage2), and init the fixed-capacity bucket cursors.
// ---------------------------------------------------------------------------
__global__ void prep_k(const float* __restrict__ m1, const float* __restrict__ Wih1,
                       const float* __restrict__ bih1, const float* __restrict__ bhh1,
                       const float* __restrict__ m2, const float* __restrict__ Wih2,
                       const float* __restrict__ bih2, const float* __restrict__ bhh2,
                       const float* __restrict__ wtW1, const float* __restrict__ wtb1,
                       const float* __restrict__ wtW2, const float* __restrict__ wtb2,
                       const float* __restrict__ Wout, const float* __restrict__ bout,
                       const float* __restrict__ W2,
                       float* __restrict__ Wn1, float* __restrict__ Wn2,
                       float* __restrict__ wsum, float* __restrict__ bsum,
                       unsigned short* __restrict__ W2bh, unsigned short* __restrict__ W2bl,
                       int* __restrict__ bfill, int NBK) {
    __shared__ float nm[32];   // new_mem1 [0..15], new_mem2 [16..31]
    int t = threadIdx.x;
    if (t < 32) {
        int L = t >> 4, j = t & 15;
        const float* m   = L ? m2   : m1;
        const float* Wih = L ? Wih2 : Wih1;
        const float* bih = L ? bih2 : bih1;
        const float* bhh = L ? bhh2 : bhh1;
        float gr = bih[j], gz = bih[16 + j], gn = bih[32 + j];
        for (int k = 0; k < 16; ++k) {
            float mk = m[k];
            gr += Wih[j * 16 + k] * mk;
            gz += Wih[(16 + j) * 16 + k] * mk;
            gn += Wih[(32 + j) * 16 + k] * mk;
        }
        float r = 1.f / (1.f + expf(-(gr + bhh[j])));
        float z = 1.f / (1.f + expf(-(gz + bhh[16 + j])));
        float n = tanhf(gn + r * bhh[32 + j]);
        nm[t] = (1.f - z) * n;          // + z*h, h==0
    }
    __syncthreads();
    float s1 = wtb1[t], s2 = wtb2[t];
    for (int k = 0; k < 16; ++k) {
        s1 += wtW1[t * 16 + k] * nm[k];
        s2 += wtW2[t * 16 + k] * nm[16 + k];
    }
    Wn1[t] = s1;
    Wn2[t] = s2;
    // W2 [16][256] -> bf16 hi/lo split (row-major, MFMA B-fragment friendly)
    for (int i = t; i < 4096; i += 256) {
        float v = W2[i];
        unsigned short h = f2bf(v);
        W2bh[i] = h;
        W2bl[i] = f2bf(v - bf2f(h));
    }
    if (t < 16) wsum[t] = Wout[t] + Wout[16 + t];
    if (t == 0) bsum[0] = bout[0] + bout[1];
    for (int i = t; i < NBK; i += 256) bfill[i] = i * BCAP;
}

// Split W1 into bf16 hi/lo pair (for split-bf16 MFMA GEMM). 32768 elems.
__global__ void wsplit_k(const float* __restrict__ W1,
                         unsigned short* __restrict__ W1h,
                         unsigned short* __restrict__ W1l) {
    int i = blockIdx.x * 256 + threadIdx.x;
    float v = W1[i];
    unsigned short h = f2bf(v);
    W1h[i] = h;
    W1l[i] = f2bf(v - bf2f(h));
}

// ---------------------------------------------------------------------------
// CSR build: bscat (fixed-base buckets) -> cscan (1 block) -> bproc.
// ---------------------------------------------------------------------------
__global__ void bscat_k(const int* __restrict__ row, const int* __restrict__ col,
                        int* __restrict__ bfill, int2* __restrict__ stage,
                        int E, int NBK) {
    __shared__ int lcnt[NBKMAX];
    __shared__ int lbase[NBKMAX];
    int t = threadIdx.x;
    for (int i = t; i < NBK; i += 256) lcnt[i] = 0;
    __syncthreads();
    int base = blockIdx.x * 4096;
    int r[16], d[16], sl[16];
#pragma unroll
    for (int i = 0; i < 16; ++i) {
        int e = base + i * 256 + t;
        if (e < E) {
            r[i]  = row[e];
            d[i]  = col[e];
            sl[i] = atomicAdd(&lcnt[d[i] >> BSH2], 1);
        } else d[i] = -1;
    }
    __syncthreads();
    for (int i = t; i < NBK; i += 256)
        lbase[i] = lcnt[i] ? atomicAdd(bfill + i, lcnt[i]) : 0;
    __syncthreads();
#pragma unroll
    for (int i = 0; i < 16; ++i) {
        if (d[i] >= 0)
            stage[lbase[d[i] >> BSH2] + sl[i]] = make_int2(r[i], d[i]);
    }
}

// single block: counts from bfill, exclusive scan -> contiguous CSR bases
__global__ __launch_bounds__(512) void cscan_k(const int* __restrict__ bfill,
                                               int* __restrict__ bbase2,
                                               int* __restrict__ off,
                                               int NBK, int N, int E) {
    __shared__ int s[512];
    int t = threadIdx.x;
    int v = (t < NBK) ? (bfill[t] - t * BCAP) : 0;
    s[t] = v;
    __syncthreads();
    for (int d = 1; d < 512; d <<= 1) {
        int u = (t >= d) ? s[t - d] : 0;
        __syncthreads();
        s[t] += u;
        __syncthreads();
    }
    if (t < NBK) bbase2[t] = s[t] - v;
    if (t == 0) { bbase2[NBK] = E; off[N] = E; }
}

// one block per 256-dest bucket: LDS hist (1 counter/thread) -> 256-scan ->
// off/dis -> in-window scatter (~32 KB window, L2-resident). LDS atomics only.
__global__ void bproc_k(const int2* __restrict__ stage, const int* __restrict__ bbase2,
                        int* __restrict__ off, float* __restrict__ dis,
                        int* __restrict__ srcs, int N) {
    __shared__ int lh[BKS];    // counts, then cursors
    __shared__ int ssc[BKS];   // scan
    const int b  = blockIdx.x;
    const int t  = threadIdx.x;
    const int sb = b * BCAP;                     // stage read base
    const int e0 = bbase2[b];
    const int cnt = bbase2[b + 1] - e0;
    lh[t] = 0;
    __syncthreads();
    for (int i = t; i < cnt; i += 256) {
        int2 v = stage[sb + i];
        atomicAdd(&lh[v.y & (BKS - 1)], 1);
    }
    __syncthreads();
    int c = lh[t];
    ssc[t] = c;
    __syncthreads();
    for (int d = 1; d < 256; d <<= 1) {
        int u = (t >= d) ? ssc[t - d] : 0;
        __syncthreads();
        ssc[t] += u;
        __syncthreads();
    }
    int ex = ssc[t] - c;       // exclusive offset within bucket
    {
        int node = b * BKS + t;
        if (node < N) {
            off[node] = e0 + ex;
            dis[node] = rsqrtf((float)(c + 1));   // in-degree + self-loop
        }
    }
    __syncthreads();
    lh[t] = ex;                // cursors
    __syncthreads();
    for (int i = t; i < cnt; i += 256) {
        int2 w = stage[sb + i];
        int pos = e0 + atomicAdd(&lh[w.y & (BKS - 1)], 1);
        srcs[pos] = w.x;
    }
}

// ---------------------------------------------------------------------------
// Fused MLP v6: all-MFMA, latency-chain free.
//   P0: x loads + W1 B-frag preload (VGPR) + bf16 hi/lo staging
//   P1: GEMM1 (256-wide) split-bf16 MFMA, B register-resident
//   P2: W2 B-frag preload + h1 -> bf16 hi/lo LDS (overlay x tile)
//   P3: GEMM2 (64x16x256) split-bf16 MFMA, K halved across wave pairs
//   P4: partial combine + b2/lrelu + Wn1 (16x16) + dis scale + store (bf16)
// Output feature table is bf16 (32 B/row): N*16*2 = 3.2 MB < 4 MiB per-XCD
// L2, so the random row-gathers in gather1/2 become L2-resident.
// ---------------------------------------------------------------------------
__global__ __launch_bounds__(512, 4) void mlp_k(
        const float* __restrict__ x,
        const unsigned short* __restrict__ W1h,
        const unsigned short* __restrict__ W1l,
        const float* __restrict__ b1,
        const unsigned short* __restrict__ W2bh,
        const unsigned short* __restrict__ W2bl,
        const float* __restrict__ b2,
        const float* __restrict__ Wn1,
        const float* __restrict__ dis,
        unsigned short* __restrict__ xl, int N) {
    __shared__ float sbuf[19456];                    // 77824 B -> 2 blocks/CU
    unsigned short* xh  = (unsigned short*)sbuf;     // x  [64][136] bf16 hi
    unsigned short* xlo = xh + 8704;                 // x  [64][136] bf16 lo
    unsigned short* h1h = (unsigned short*)sbuf;     // h1 [64][264] bf16 hi (overlay)
    unsigned short* h1l = h1h + 16896;               // h1 [64][264] bf16 lo
    float*          h2p = sbuf + 16896;              // [2][64][20] f32 partials

    const int t      = threadIdx.x;
    const int nl     = t & 63;
    const int q      = __builtin_amdgcn_readfirstlane(t >> 6);  // wave 0..7
    const int lane15 = t & 15;
    const int quad   = (t & 63) >> 4;
    const int node   = blockIdx.x * 64 + nl;
    const bool valid = node < N;

    // ---- P0a: issue x loads (wave q stages k in [q*16, q*16+16)) ----
    float4 xv[4];
    if (valid) {
        const float4* xr = (const float4*)(x + (size_t)node * 128) + q * 4;
#pragma unroll
        for (int kk = 0; kk < 4; ++kk) xv[kk] = xr[kk];
    }

    // ---- P0b: preload W1 B-fragments (16 x b128, L2-hot; latency hides
    //           under x-load wait + conversion + barrier) ----
    bf16x8 w1hf[2][4], w1lf[2][4];                   // [nt][ks]
#pragma unroll
    for (int nt = 0; nt < 2; ++nt)
#pragma unroll
        for (int ks = 0; ks < 4; ++ks) {
            size_t wo = (size_t)(q * 32 + nt * 16 + lane15) * 128 + ks * 32 + quad * 8;
            w1hf[nt][ks] = *(const bf16x8*)(W1h + wo);
            w1lf[nt][ks] = *(const bf16x8*)(W1l + wo);
        }

    // ---- P0c: convert + stage x ----
    {
        unsigned* xh32 = (unsigned*)xh;
        unsigned* xl32 = (unsigned*)xlo;
        int base = nl * 68 + q * 8;                  // uint index (row stride 68)
        if (valid) {
#pragma unroll
            for (int kk = 0; kk < 4; ++kk) {
                float4 v = xv[kk];
                unsigned short hx = f2bf(v.x), hy = f2bf(v.y);
                unsigned short hz = f2bf(v.z), hw = f2bf(v.w);
                unsigned short lx = f2bf(v.x - bf2f(hx)), ly = f2bf(v.y - bf2f(hy));
                unsigned short lz = f2bf(v.z - bf2f(hz)), lw = f2bf(v.w - bf2f(hw));
                *(uint2*)(xh32 + base + kk * 2) =
                    make_uint2((unsigned)hx | ((unsigned)hy << 16),
                               (unsigned)hz | ((unsigned)hw << 16));
                *(uint2*)(xl32 + base + kk * 2) =
                    make_uint2((unsigned)lx | ((unsigned)ly << 16),
                               (unsigned)lz | ((unsigned)lw << 16));
            }
        } else {
#pragma unroll
            for (int kk = 0; kk < 4; ++kk) {
                *(uint2*)(xh32 + base + kk * 2) = make_uint2(0u, 0u);
                *(uint2*)(xl32 + base + kk * 2) = make_uint2(0u, 0u);
            }
        }
    }
    __syncthreads();

    // ---- P1: GEMM1, wave q owns hu in [q*32, q*32+32); B in registers ----
    f32x4 acc[4][2];
#pragma unroll
    for (int mt = 0; mt < 4; ++mt)
#pragma unroll
        for (int nt = 0; nt < 2; ++nt)
            acc[mt][nt] = (f32x4){0.f, 0.f, 0.f, 0.f};

#pragma unroll
    for (int ks = 0; ks < 4; ++ks) {
        const int koff = ks * 32 + quad * 8;
#pragma unroll
        for (int mt = 0; mt < 4; ++mt) {
            bf16x8 ah = *(const bf16x8*)(xh  + (16 * mt + lane15) * 136 + koff);
            bf16x8 al = *(const bf16x8*)(xlo + (16 * mt + lane15) * 136 + koff);
#pragma unroll
            for (int nt = 0; nt < 2; ++nt) {
                acc[mt][nt] = __builtin_amdgcn_mfma_f32_16x16x32_bf16(ah, w1hf[nt][ks], acc[mt][nt], 0, 0, 0);
                acc[mt][nt] = __builtin_amdgcn_mfma_f32_16x16x32_bf16(ah, w1lf[nt][ks], acc[mt][nt], 0, 0, 0);
                acc[mt][nt] = __builtin_amdgcn_mfma_f32_16x16x32_bf16(al, w1hf[nt][ks], acc[mt][nt], 0, 0, 0);
            }
        }
    }
    __syncthreads();   // x tile dead; safe to overlay h1

    // ---- P2a: preload W2 B-fragments for this wave's K-half ----
    const int kh  = q >> 2;        // K-half for stage2
    const int mt2 = q & 3;         // m-tile for stage2
    bf16x8 w2hf[4], w2lf[4];
#pragma unroll
    for (int ks2 = 0; ks2 < 4; ++ks2) {
        int wo = lane15 * 256 + (kh * 4 + ks2) * 32 + quad * 8;
        w2hf[ks2] = *(const bf16x8*)(W2bh + wo);
        w2lf[ks2] = *(const bf16x8*)(W2bl + wo);
    }

    // ---- P2b: epilogue GEMM1 -> h1 bf16 hi/lo in LDS ----
#pragma unroll
    for (int nt = 0; nt < 2; ++nt) {
        int hu = q * 32 + nt * 16 + lane15;
        float bb = b1[hu];
#pragma unroll
        for (int mt = 0; mt < 4; ++mt) {
            int row0 = 16 * mt + quad * 4;
#pragma unroll
            for (int r = 0; r < 4; ++r) {
                float v = lrelu(acc[mt][nt][r] + bb);
                unsigned short h = f2bf(v);
                h1h[(row0 + r) * 264 + hu] = h;
                h1l[(row0 + r) * 264 + hu] = f2bf(v - bf2f(h));
            }
        }
    }
    __syncthreads();

    // ---- P3: GEMM2 partial (wave q: rows 16*mt2.., K-half kh) ----
    f32x4 a2 = (f32x4){0.f, 0.f, 0.f, 0.f};
#pragma unroll
    for (int ks2 = 0; ks2 < 4; ++ks2) {
        const int koff = (kh * 4 + ks2) * 32 + quad * 8;
        bf16x8 ah = *(const bf16x8*)(h1h + (16 * mt2 + lane15) * 264 + koff);
        bf16x8 al = *(const bf16x8*)(h1l + (16 * mt2 + lane15) * 264 + koff);
        a2 = __builtin_amdgcn_mfma_f32_16x16x32_bf16(ah, w2hf[ks2], a2, 0, 0, 0);
        a2 = __builtin_amdgcn_mfma_f32_16x16x32_bf16(ah, w2lf[ks2], a2, 0, 0, 0);
        a2 = __builtin_amdgcn_mfma_f32_16x16x32_bf16(al, w2hf[ks2], a2, 0, 0, 0);
    }
    {
        // h2p[kh][row][j], row = 16*mt2 + quad*4 + r, j = lane15, stride 20
        float* dst = h2p + kh * 1280 + (16 * mt2 + quad * 4) * 20 + lane15;
        dst[0] = a2[0]; dst[20] = a2[1]; dst[40] = a2[2]; dst[60] = a2[3];
    }
    __syncthreads();

    // ---- P4: combine partials, b2 + lrelu, Wn1 (16x16), dis scale, store ----
    {
        const f32x4* pa = (const f32x4*)(h2p + nl * 20);
        const f32x4* pb = (const f32x4*)(h2p + 1280 + nl * 20);
        f32x4 s[4];
#pragma unroll
        for (int i = 0; i < 4; ++i) s[i] = pa[i] + pb[i];
        float o0 = 0.f, o1 = 0.f;
        const float* wr0 = Wn1 + (2 * q) * 16;       // uniform -> s_load (one-shot)
        const float* wr1 = Wn1 + (2 * q + 1) * 16;
#pragma unroll
        for (int j = 0; j < 16; ++j) {
            float h = lrelu(s[j >> 2][j & 3] + b2[j]);
            o0 = fmaf(wr0[j], h, o0);
            o1 = fmaf(wr1[j], h, o1);
        }
        if (valid) {
            float d = dis[node];
            unsigned pk = (unsigned)f2bf(d * o0) | ((unsigned)f2bf(d * o1) << 16);
            *(unsigned*)(xl + (size_t)node * 16 + 2 * q) = pk;
        }
    }
}

// ---------------------------------------------------------------------------
// Gather layer 1 (wave per node, 4-deep batched gathers — R11-proven).
// Feature table in bf16: 32 B rows, 3.2 MB table -> per-XCD L2-resident.
// ---------------------------------------------------------------------------
__global__ void gather1_k(const int* __restrict__ off, const int* __restrict__ srcs,
                          const float* __restrict__ dis,
                          const unsigned short* __restrict__ xin,
                          const float* __restrict__ bias, const float* __restrict__ Wn2,
                          unsigned short* __restrict__ xout, int N) {
    __shared__ float w[256];             // transposed: w[j*16+c] = Wn2[c*16+j]
    {
        int j = threadIdx.x >> 4, c = threadIdx.x & 15;
        w[threadIdx.x] = Wn2[c * 16 + j];
    }
    __syncthreads();
    int t = blockIdx.x * 256 + threadIdx.x;
    int n = t >> 6;
    if (n >= N) return;
    int lane = t & 63, sub = lane >> 4, c = lane & 15;
    float acc = (sub == 0) ? bf2f(xin[(size_t)n * 16 + c]) : 0.f;   // self term
    int e  = off[n] + sub;
    int e1 = off[n + 1];
    for (; e + 12 < e1; e += 16) {
        int s0 = srcs[e], s1 = srcs[e + 4], s2 = srcs[e + 8], s3 = srcs[e + 12];
        float v0 = bf2f(xin[(size_t)s0 * 16 + c]);
        float v1 = bf2f(xin[(size_t)s1 * 16 + c]);
        float v2 = bf2f(xin[(size_t)s2 * 16 + c]);
        float v3 = bf2f(xin[(size_t)s3 * 16 + c]);
        acc += (v0 + v1) + (v2 + v3);
    }
    for (; e < e1; e += 4)
        acc += bf2f(xin[(size_t)srcs[e] * 16 + c]);
    acc += __shfl_xor(acc, 16);
    acc += __shfl_xor(acc, 32);
    float d = dis[n];
    float h = lrelu(fmaf(d, acc, bias[c]));
    float o = 0.f;
#pragma unroll
    for (int j = 0; j < 16; ++j) o = fmaf(w[j * 16 + c], __shfl(h, j, 16), o);
    if (sub == 0) xout[(size_t)n * 16 + c] = f2bf(d * o);
}

// ---------------------------------------------------------------------------
// Gather layer 2 + final projection (same 4-deep batching, bf16 table)
// ---------------------------------------------------------------------------
__global__ void gather2_k(const int* __restrict__ off, const int* __restrict__ srcs,
                          const float* __restrict__ dis,
                          const unsigned short* __restrict__ xin,
                          const float* __restrict__ bias, const float* __restrict__ wsum,
                          const float* __restrict__ bsum, float* __restrict__ out, int N) {
    int t = blockIdx.x * 256 + threadIdx.x;
    int n = t >> 6;
    if (n >= N) return;
    int lane = t & 63, sub = lane >> 4, c = lane & 15;
    float acc = (sub == 0) ? bf2f(xin[(size_t)n * 16 + c]) : 0.f;
    int e  = off[n] + sub;
    int e1 = off[n + 1];
    for (; e + 12 < e1; e += 16) {
        int s0 = srcs[e], s1 = srcs[e + 4], s2 = srcs[e + 8], s3 = srcs[e + 12];
        float v0 = bf2f(xin[(size_t)s0 * 16 + c]);
        float v1 = bf2f(xin[(size_t)s1 * 16 + c]);
        float v2 = bf2f(xin[(size_t)s2 * 16 + c]);
        float v3 = bf2f(xin[(size_t)s3 * 16 + c]);
        acc += (v0 + v1) + (v2 + v3);
    }
    for (; e < e1; e += 4)
        acc += bf2f(xin[(size_t)srcs[e] * 16 + c]);
    acc += __shfl_xor(acc, 16);
    acc += __shfl_xor(acc, 32);
    float v = wsum[c] * lrelu(fmaf(dis[n], acc, bias[c]));
#pragma unroll
    for (int m = 1; m < 16; m <<= 1) v += __shfl_xor(v, m);
    if (lane == 0) out[n] = v + bsum[0];
}

// ---------------------------------------------------------------------------
extern "C" void kernel_launch(void* const* d_in, const int* in_sizes, int n_in,
                              void* d_out, int out_size, void* d_ws, size_t ws_size,
                              hipStream_t stream) {
    const float* x      = (const float*)d_in[0];
    const int*   edge   = (const int*)d_in[1];
    const float* W1     = (const float*)d_in[2];
    const float* b1     = (const float*)d_in[3];
    const float* W2     = (const float*)d_in[4];
    const float* b2     = (const float*)d_in[5];
    const float* mem1   = (const float*)d_in[6];
    const float* g1_Wih = (const float*)d_in[7];
    const float* g1_bih = (const float*)d_in[9];
    const float* g1_bhh = (const float*)d_in[10];
    const float* wt1_W  = (const float*)d_in[11];
    const float* wt1_b  = (const float*)d_in[12];
    const float* gcn1_b = (const float*)d_in[13];
    const float* mem2   = (const float*)d_in[14];
    const float* g2_Wih = (const float*)d_in[15];
    const float* g2_bih = (const float*)d_in[17];
    const float* g2_bhh = (const float*)d_in[18];
    const float* wt2_W  = (const float*)d_in[19];
    const float* wt2_b  = (const float*)d_in[20];
    const float* gcn2_b = (const float*)d_in[21];
    const float* Wout   = (const float*)d_in[22];
    const float* bout   = (const float*)d_in[23];
    float* out = (float*)d_out;

    const int N = in_sizes[0] / 128;
    const int E = in_sizes[1] / 2;
    const int* row = edge;
    const int* col = edge + E;

    const int NBK = (N + BKS - 1) >> BSH2;   // coarse buckets (391 @ N=100k)
    const int gM  = (N + 63) / 64;           // mlp blocks (64 nodes, 512 thr)
    const int gG  = (N * 64 + 255) / 256;    // gather blocks (wave per node)
    const int gB  = (E + 4095) / 4096;       // bscat blocks

    float* ws    = (float*)d_ws;
    float* bufA  = ws;                        // [N*16] bf16 used (alloc float-sized)
    float* bufB  = bufA + (size_t)N * 16;     // [N*16] bf16 used
    float* dis   = bufB + (size_t)N * 16;     // [N]
    float* sm    = dis + N;                   // smalls
    float* Wn1   = sm;
    float* Wn2   = sm + 256;
    float* wsum  = sm + 512;
    float* bsum  = sm + 528;
    unsigned short* W2bh = (unsigned short*)(sm + 544);   // [16*256] bf16 hi (8 KB)
    unsigned short* W2bl = (unsigned short*)(sm + 2592);  // [16*256] bf16 lo (8 KB)
    unsigned short* W1h = (unsigned short*)(sm + 4640);   // [256*128] bf16 hi
    unsigned short* W1l = (unsigned short*)(sm + 21024);  // [256*128] bf16 lo
    int*   bfill = (int*)(sm + 37408);        // [NBKMAX]
    int*   bbase2= bfill + NBKMAX;            // [NBKMAX+1]
    int*   off   = bbase2 + NBKMAX + 1;       // [N+1]
    int*   srcs  = off + N + 1;               // [E]
    // stage: 16B-aligned int2[NBK*BCAP]
    size_t stoff = (size_t)(srcs + E - (int*)d_ws);
    stoff = (stoff + 3) & ~(size_t)3;
    int2*  stage = (int2*)((int*)d_ws + stoff);

    prep_k<<<1, 256, 0, stream>>>(mem1, g1_Wih, g1_bih, g1_bhh,
                                  mem2, g2_Wih, g2_bih, g2_bhh,
                                  wt1_W, wt1_b, wt2_W, wt2_b,
                                  Wout, bout, W2, Wn1, Wn2, wsum, bsum,
                                  W2bh, W2bl, bfill, NBK);
    wsplit_k<<<128, 256, 0, stream>>>(W1, W1h, W1l);
    bscat_k<<<gB, 256, 0, stream>>>(row, col, bfill, stage, E, NBK);
    cscan_k<<<1, 512, 0, stream>>>(bfill, bbase2, off, NBK, N, E);
    bproc_k<<<NBK, 256, 0, stream>>>(stage, bbase2, off, dis, srcs, N);
    mlp_k<<<gM, 512, 0, stream>>>(x, W1h, W1l, b1, W2bh, W2bl, b2, Wn1, dis,
                                  (unsigned short*)bufA, N);
    gather1_k<<<gG, 256, 0, stream>>>(off, srcs, dis, (unsigned short*)bufA,
                                      gcn1_b, Wn2, (unsigned short*)bufB, N);
    gather2_k<<<gG, 256, 0, stream>>>(off, srcs, dis, (unsigned short*)bufB,
                                      gcn2_b, wsum, bsum, out, N);
}

// Round 4
// 369.759 us; speedup vs baseline: 1.1001x; 1.0155x over previous
//
#include <hip/hip_runtime.h>
#include <math.h>

#define SLOPE 0.01f
#define BKS   256        // dests per bucket (R12: 1024 -> 98 blocks was launch-width-bound)
#define BSH2  8          // log2(BKS)
#define NBKMAX 512       // max coarse buckets (N <= 131072)
#define BCAP  10240      // fixed bucket capacity (mean 8192 + 22 sigma)

typedef short  bf16x8 __attribute__((ext_vector_type(8)));
typedef float  f32x4  __attribute__((ext_vector_type(4)));

__device__ __forceinline__ float lrelu(float v) { return v >= 0.f ? v : SLOPE * v; }

__device__ __forceinline__ unsigned short f2bf(float v) {
    unsigned u = __float_as_uint(v);
    return (unsigned short)((u + 0x7FFFu + ((u >> 16) & 1u)) >> 16);   // RNE
}
__device__ __forceinline__ float bf2f(unsigned short b) {
    return __uint_as_float(((unsigned)b) << 16);
}

// ---------------------------------------------------------------------------
// GRU step (h0=0), regenerate GCN weights, fold Wout/bout, split W2 to bf16
// hi/lo (for MFMA stage2), and init the fixed-capacity bucket cursors.
// ---------------------------------------------------------------------------
__global__ void prep_k(const float* __restrict__ m1, const float* __restrict__ Wih1,
                       const float* __restrict__ bih1, const float* __restrict__ bhh1,
                       const float* __restrict__ m2, const float* __restrict__ Wih2,
                       const float* __restrict__ bih2, const float* __restrict__ bhh2,
                       const float* __restrict__ wtW1, const float* __restrict__ wtb1,
                       const float* __restrict__ wtW2, const float* __restrict__ wtb2,
                       const float* __restrict__ Wout, const float* __restrict__ bout,
                       const float* __restrict__ W2,
                       float* __restrict__ Wn1, float* __restrict__ Wn2,
                       float* __restrict__ wsum, float* __restrict__ bsum,
                       unsigned short* __restrict__ W2bh, unsigned short* __restrict__ W2bl,
                       int* __restrict__ bfill, int NBK) {
    __shared__ float nm[32];   // new_mem1 [0..15], new_mem2 [16..31]
    int t = threadIdx.x;
    if (t < 32) {
        int L = t >> 4, j = t & 15;
        const float* m   = L ? m2   : m1;
        const float* Wih = L ? Wih2 : Wih1;
        const float* bih = L ? bih2 : bih1;
        const float* bhh = L ? bhh2 : bhh1;
        float gr = bih[j], gz = bih[16 + j], gn = bih[32 + j];
        for (int k = 0; k < 16; ++k) {
            float mk = m[k];
            gr += Wih[j * 16 + k] * mk;
            gz += Wih[(16 + j) * 16 + k] * mk;
            gn += Wih[(32 + j) * 16 + k] * mk;
        }
        float r = 1.f / (1.f + expf(-(gr + bhh[j])));
        float z = 1.f / (1.f + expf(-(gz + bhh[16 + j])));
        float n = tanhf(gn + r * bhh[32 + j]);
        nm[t] = (1.f - z) * n;          // + z*h, h==0
    }
    __syncthreads();
    float s1 = wtb1[t], s2 = wtb2[t];
    for (int k = 0; k < 16; ++k) {
        s1 += wtW1[t * 16 + k] * nm[k];
        s2 += wtW2[t * 16 + k] * nm[16 + k];
    }
    Wn1[t] = s1;
    Wn2[t] = s2;
    // W2 [16][256] -> bf16 hi/lo split (row-major, MFMA B-fragment friendly)
    for (int i = t; i < 4096; i += 256) {
        float v = W2[i];
        unsigned short h = f2bf(v);
        W2bh[i] = h;
        W2bl[i] = f2bf(v - bf2f(h));
    }
    if (t < 16) wsum[t] = Wout[t] + Wout[16 + t];
    if (t == 0) bsum[0] = bout[0] + bout[1];
    for (int i = t; i < NBK; i += 256) bfill[i] = i * BCAP;
}

// Split W1 into bf16 hi/lo pair (for split-bf16 MFMA GEMM). 32768 elems.
__global__ void wsplit_k(const float* __restrict__ W1,
                         unsigned short* __restrict__ W1h,
                         unsigned short* __restrict__ W1l) {
    int i = blockIdx.x * 256 + threadIdx.x;
    float v = W1[i];
    unsigned short h = f2bf(v);
    W1h[i] = h;
    W1l[i] = f2bf(v - bf2f(h));
}

// ---------------------------------------------------------------------------
// CSR build: bscat (fixed-base buckets) -> cscan (1 block) -> bproc.
// ---------------------------------------------------------------------------
__global__ void bscat_k(const int* __restrict__ row, const int* __restrict__ col,
                        int* __restrict__ bfill, int2* __restrict__ stage,
                        int E, int NBK) {
    __shared__ int lcnt[NBKMAX];
    __shared__ int lbase[NBKMAX];
    int t = threadIdx.x;
    for (int i = t; i < NBK; i += 256) lcnt[i] = 0;
    __syncthreads();
    int base = blockIdx.x * 4096;
    int r[16], d[16], sl[16];
#pragma unroll
    for (int i = 0; i < 16; ++i) {
        int e = base + i * 256 + t;
        if (e < E) {
            r[i]  = row[e];
            d[i]  = col[e];
            sl[i] = atomicAdd(&lcnt[d[i] >> BSH2], 1);
        } else d[i] = -1;
    }
    __syncthreads();
    for (int i = t; i < NBK; i += 256)
        lbase[i] = lcnt[i] ? atomicAdd(bfill + i, lcnt[i]) : 0;
    __syncthreads();
#pragma unroll
    for (int i = 0; i < 16; ++i) {
        if (d[i] >= 0)
            stage[lbase[d[i] >> BSH2] + sl[i]] = make_int2(r[i], d[i]);
    }
}

// single block: counts from bfill, exclusive scan -> contiguous CSR bases
__global__ __launch_bounds__(512) void cscan_k(const int* __restrict__ bfill,
                                               int* __restrict__ bbase2,
                                               int* __restrict__ off,
                                               int NBK, int N, int E) {
    __shared__ int s[512];
    int t = threadIdx.x;
    int v = (t < NBK) ? (bfill[t] - t * BCAP) : 0;
    s[t] = v;
    __syncthreads();
    for (int d = 1; d < 512; d <<= 1) {
        int u = (t >= d) ? s[t - d] : 0;
        __syncthreads();
        s[t] += u;
        __syncthreads();
    }
    if (t < NBK) bbase2[t] = s[t] - v;
    if (t == 0) { bbase2[NBK] = E; off[N] = E; }
}

// one block per 256-dest bucket: LDS hist (1 counter/thread) -> 256-scan ->
// off/dis -> in-window scatter (~32 KB window, L2-resident). LDS atomics only.
__global__ void bproc_k(const int2* __restrict__ stage, const int* __restrict__ bbase2,
                        int* __restrict__ off, float* __restrict__ dis,
                        int* __restrict__ srcs, int N) {
    __shared__ int lh[BKS];    // counts, then cursors
    __shared__ int ssc[BKS];   // scan
    const int b  = blockIdx.x;
    const int t  = threadIdx.x;
    const int sb = b * BCAP;                     // stage read base
    const int e0 = bbase2[b];
    const int cnt = bbase2[b + 1] - e0;
    lh[t] = 0;
    __syncthreads();
    for (int i = t; i < cnt; i += 256) {
        int2 v = stage[sb + i];
        atomicAdd(&lh[v.y & (BKS - 1)], 1);
    }
    __syncthreads();
    int c = lh[t];
    ssc[t] = c;
    __syncthreads();
    for (int d = 1; d < 256; d <<= 1) {
        int u = (t >= d) ? ssc[t - d] : 0;
        __syncthreads();
        ssc[t] += u;
        __syncthreads();
    }
    int ex = ssc[t] - c;       // exclusive offset within bucket
    {
        int node = b * BKS + t;
        if (node < N) {
            off[node] = e0 + ex;
            dis[node] = rsqrtf((float)(c + 1));   // in-degree + self-loop
        }
    }
    __syncthreads();
    lh[t] = ex;                // cursors
    __syncthreads();
    for (int i = t; i < cnt; i += 256) {
        int2 w = stage[sb + i];
        int pos = e0 + atomicAdd(&lh[w.y & (BKS - 1)], 1);
        srcs[pos] = w.x;
    }
}

// ---------------------------------------------------------------------------
// Fused MLP v7: occupancy-first.
//   P0: linear-coalesced x load (1 KB/instr per wave) + bf16 hi/lo staging
//   P1: GEMM1 (256-wide) split-bf16 MFMA (3-term, x precision preserved)
//   P2: W2 B-frag preload + h1 -> bf16 (hi ONLY) LDS (overlay x tile)
//   P3: GEMM2 (64x16x256): A single-bf16, B hi/lo split (2-term)
//   P4: partial combine + b2/lrelu + Wn1 (16x16) + dis scale + store (bf16)
// LDS 44032 B -> 3 blocks/CU (24 waves) vs v6's 2 (16 waves): more
// independent barrier streams to hide x/W1 latency (v6 was stall-bound:
// VALU 21% + MFMA ~4% real, rest idle).
// ---------------------------------------------------------------------------
__global__ __launch_bounds__(512, 6) void mlp_k(
        const float* __restrict__ x,
        const unsigned short* __restrict__ W1h,
        const unsigned short* __restrict__ W1l,
        const float* __restrict__ b1,
        const unsigned short* __restrict__ W2bh,
        const unsigned short* __restrict__ W2bl,
        const float* __restrict__ b2,
        const float* __restrict__ Wn1,
        const float* __restrict__ dis,
        unsigned short* __restrict__ xl, int N) {
    __shared__ float sbuf[11008];                    // 44032 B -> 3 blocks/CU
    unsigned short* xh  = (unsigned short*)sbuf;     // x  [64][136] bf16 hi (17408 B)
    unsigned short* xlo = xh + 8704;                 // x  [64][136] bf16 lo (17408 B)
    unsigned short* h1h = (unsigned short*)sbuf;     // h1 [64][264] bf16 (overlay, 33792 B)
    float*          h2p = sbuf + 8448;               // [2][64][20] f32 partials (10240 B)

    const int t      = threadIdx.x;
    const int nl     = t & 63;
    const int q      = __builtin_amdgcn_readfirstlane(t >> 6);  // wave 0..7
    const int lane15 = t & 15;
    const int quad   = (t & 63) >> 4;
    const int node   = blockIdx.x * 64 + nl;
    const bool valid = node < N;

    // ---- P0: linear-coalesced x load + bf16 hi/lo staging ----
    // Block tile = x[64 nodes][128] = 2048 float4. Thread t handles flat
    // float4 indices t + 512*kk: row=(idx>>5), k=4*(idx&31). Wave-contiguous
    // 1 KB per load instruction (was 16 B/lane at 512 B stride).
    {
        const float4* x4 = (const float4*)x;
        const size_t tb = (size_t)blockIdx.x * 2048;
        unsigned* xh32 = (unsigned*)xh;
        unsigned* xl32 = (unsigned*)xlo;
#pragma unroll
        for (int kk = 0; kk < 4; ++kk) {
            int idx  = kk * 512 + t;
            int row  = idx >> 5;                 // 0..63
            int col4 = idx & 31;                 // k = 4*col4
            float4 v = make_float4(0.f, 0.f, 0.f, 0.f);
            if (blockIdx.x * 64 + row < N) v = x4[tb + idx];
            unsigned short hx = f2bf(v.x), hy = f2bf(v.y);
            unsigned short hz = f2bf(v.z), hw = f2bf(v.w);
            unsigned short lx = f2bf(v.x - bf2f(hx)), ly = f2bf(v.y - bf2f(hy));
            unsigned short lz = f2bf(v.z - bf2f(hz)), lw = f2bf(v.w - bf2f(hw));
            int base = row * 68 + col4 * 2;      // uint index (row stride 68)
            *(uint2*)(xh32 + base) =
                make_uint2((unsigned)hx | ((unsigned)hy << 16),
                           (unsigned)hz | ((unsigned)hw << 16));
            *(uint2*)(xl32 + base) =
                make_uint2((unsigned)lx | ((unsigned)ly << 16),
                           (unsigned)lz | ((unsigned)lw << 16));
        }
    }
    __syncthreads();

    // ---- P1: GEMM1, wave q owns hu in [q*32, q*32+32) ----
    f32x4 acc[4][2];
#pragma unroll
    for (int mt = 0; mt < 4; ++mt)
#pragma unroll
        for (int nt = 0; nt < 2; ++nt)
            acc[mt][nt] = (f32x4){0.f, 0.f, 0.f, 0.f};

#pragma unroll
    for (int ks = 0; ks < 4; ++ks) {
        const int koff = ks * 32 + quad * 8;
#pragma unroll
        for (int mt = 0; mt < 4; ++mt) {
            bf16x8 ah = *(const bf16x8*)(xh  + (16 * mt + lane15) * 136 + koff);
            bf16x8 al = *(const bf16x8*)(xlo + (16 * mt + lane15) * 136 + koff);
#pragma unroll
            for (int nt = 0; nt < 2; ++nt) {
                size_t wo = (size_t)(q * 32 + nt * 16 + lane15) * 128 + koff;
                bf16x8 bh = *(const bf16x8*)(W1h + wo);
                bf16x8 bl = *(const bf16x8*)(W1l + wo);
                acc[mt][nt] = __builtin_amdgcn_mfma_f32_16x16x32_bf16(ah, bh, acc[mt][nt], 0, 0, 0);
                acc[mt][nt] = __builtin_amdgcn_mfma_f32_16x16x32_bf16(ah, bl, acc[mt][nt], 0, 0, 0);
                acc[mt][nt] = __builtin_amdgcn_mfma_f32_16x16x32_bf16(al, bh, acc[mt][nt], 0, 0, 0);
            }
        }
    }
    __syncthreads();   // x tile dead; safe to overlay h1

    // ---- P2a: preload W2 B-fragments for this wave's K-half ----
    const int kh  = q >> 2;        // K-half for stage2
    const int mt2 = q & 3;         // m-tile for stage2
    bf16x8 w2hf[4], w2lf[4];
#pragma unroll
    for (int ks2 = 0; ks2 < 4; ++ks2) {
        int wo = lane15 * 256 + (kh * 4 + ks2) * 32 + quad * 8;
        w2hf[ks2] = *(const bf16x8*)(W2bh + wo);
        w2lf[ks2] = *(const bf16x8*)(W2bl + wo);
    }

    // ---- P2b: epilogue GEMM1 -> h1 bf16 (hi only) in LDS ----
#pragma unroll
    for (int nt = 0; nt < 2; ++nt) {
        int hu = q * 32 + nt * 16 + lane15;
        float bb = b1[hu];
#pragma unroll
        for (int mt = 0; mt < 4; ++mt) {
            int row0 = 16 * mt + quad * 4;
#pragma unroll
            for (int r = 0; r < 4; ++r) {
                float v = lrelu(acc[mt][nt][r] + bb);
                h1h[(row0 + r) * 264 + hu] = f2bf(v);
            }
        }
    }
    __syncthreads();

    // ---- P3: GEMM2 partial (wave q: rows 16*mt2.., K-half kh); A bf16,
    //          B split hi/lo (2-term) ----
    f32x4 a2 = (f32x4){0.f, 0.f, 0.f, 0.f};
#pragma unroll
    for (int ks2 = 0; ks2 < 4; ++ks2) {
        const int koff = (kh * 4 + ks2) * 32 + quad * 8;
        bf16x8 ah = *(const bf16x8*)(h1h + (16 * mt2 + lane15) * 264 + koff);
        a2 = __builtin_amdgcn_mfma_f32_16x16x32_bf16(ah, w2hf[ks2], a2, 0, 0, 0);
        a2 = __builtin_amdgcn_mfma_f32_16x16x32_bf16(ah, w2lf[ks2], a2, 0, 0, 0);
    }
    {
        // h2p[kh][row][j], row = 16*mt2 + quad*4 + r, j = lane15, stride 20
        float* dst = h2p + kh * 1280 + (16 * mt2 + quad * 4) * 20 + lane15;
        dst[0] = a2[0]; dst[20] = a2[1]; dst[40] = a2[2]; dst[60] = a2[3];
    }
    __syncthreads();

    // ---- P4: combine partials, b2 + lrelu, Wn1 (16x16), dis scale, store ----
    {
        const f32x4* pa = (const f32x4*)(h2p + nl * 20);
        const f32x4* pb = (const f32x4*)(h2p + 1280 + nl * 20);
        f32x4 s[4];
#pragma unroll
        for (int i = 0; i < 4; ++i) s[i] = pa[i] + pb[i];
        float o0 = 0.f, o1 = 0.f;
        const float* wr0 = Wn1 + (2 * q) * 16;       // uniform -> s_load (one-shot)
        const float* wr1 = Wn1 + (2 * q + 1) * 16;
#pragma unroll
        for (int j = 0; j < 16; ++j) {
            float h = lrelu(s[j >> 2][j & 3] + b2[j]);
            o0 = fmaf(wr0[j], h, o0);
            o1 = fmaf(wr1[j], h, o1);
        }
        if (valid) {
            float d = dis[node];
            unsigned pk = (unsigned)f2bf(d * o0) | ((unsigned)f2bf(d * o1) << 16);
            *(unsigned*)(xl + (size_t)node * 16 + 2 * q) = pk;
        }
    }
}

// ---------------------------------------------------------------------------
// Gather layer 1 (wave per node, 4-deep batched gathers — R11-proven).
// Feature table in bf16: 32 B rows, 3.2 MB table -> per-XCD L2-resident.
// ---------------------------------------------------------------------------
__global__ void gather1_k(const int* __restrict__ off, const int* __restrict__ srcs,
                          const float* __restrict__ dis,
                          const unsigned short* __restrict__ xin,
                          const float* __restrict__ bias, const float* __restrict__ Wn2,
                          unsigned short* __restrict__ xout, int N) {
    __shared__ float w[256];             // transposed: w[j*16+c] = Wn2[c*16+j]
    {
        int j = threadIdx.x >> 4, c = threadIdx.x & 15;
        w[threadIdx.x] = Wn2[c * 16 + j];
    }
    __syncthreads();
    int t = blockIdx.x * 256 + threadIdx.x;
    int n = t >> 6;
    if (n >= N) return;
    int lane = t & 63, sub = lane >> 4, c = lane & 15;
    float acc = (sub == 0) ? bf2f(xin[(size_t)n * 16 + c]) : 0.f;   // self term
    int e  = off[n] + sub;
    int e1 = off[n + 1];
    for (; e + 12 < e1; e += 16) {
        int s0 = srcs[e], s1 = srcs[e + 4], s2 = srcs[e + 8], s3 = srcs[e + 12];
        float v0 = bf2f(xin[(size_t)s0 * 16 + c]);
        float v1 = bf2f(xin[(size_t)s1 * 16 + c]);
        float v2 = bf2f(xin[(size_t)s2 * 16 + c]);
        float v3 = bf2f(xin[(size_t)s3 * 16 + c]);
        acc += (v0 + v1) + (v2 + v3);
    }
    for (; e < e1; e += 4)
        acc += bf2f(xin[(size_t)srcs[e] * 16 + c]);
    acc += __shfl_xor(acc, 16);
    acc += __shfl_xor(acc, 32);
    float d = dis[n];
    float h = lrelu(fmaf(d, acc, bias[c]));
    float o = 0.f;
#pragma unroll
    for (int j = 0; j < 16; ++j) o = fmaf(w[j * 16 + c], __shfl(h, j, 16), o);
    if (sub == 0) xout[(size_t)n * 16 + c] = f2bf(d * o);
}

// ---------------------------------------------------------------------------
// Gather layer 2 + final projection (same 4-deep batching, bf16 table)
// ---------------------------------------------------------------------------
__global__ void gather2_k(const int* __restrict__ off, const int* __restrict__ srcs,
                          const float* __restrict__ dis,
                          const unsigned short* __restrict__ xin,
                          const float* __restrict__ bias, const float* __restrict__ wsum,
                          const float* __restrict__ bsum, float* __restrict__ out, int N) {
    int t = blockIdx.x * 256 + threadIdx.x;
    int n = t >> 6;
    if (n >= N) return;
    int lane = t & 63, sub = lane >> 4, c = lane & 15;
    float acc = (sub == 0) ? bf2f(xin[(size_t)n * 16 + c]) : 0.f;
    int e  = off[n] + sub;
    int e1 = off[n + 1];
    for (; e + 12 < e1; e += 16) {
        int s0 = srcs[e], s1 = srcs[e + 4], s2 = srcs[e + 8], s3 = srcs[e + 12];
        float v0 = bf2f(xin[(size_t)s0 * 16 + c]);
        float v1 = bf2f(xin[(size_t)s1 * 16 + c]);
        float v2 = bf2f(xin[(size_t)s2 * 16 + c]);
        float v3 = bf2f(xin[(size_t)s3 * 16 + c]);
        acc += (v0 + v1) + (v2 + v3);
    }
    for (; e < e1; e += 4)
        acc += bf2f(xin[(size_t)srcs[e] * 16 + c]);
    acc += __shfl_xor(acc, 16);
    acc += __shfl_xor(acc, 32);
    float v = wsum[c] * lrelu(fmaf(dis[n], acc, bias[c]));
#pragma unroll
    for (int m = 1; m < 16; m <<= 1) v += __shfl_xor(v, m);
    if (lane == 0) out[n] = v + bsum[0];
}

// ---------------------------------------------------------------------------
extern "C" void kernel_launch(void* const* d_in, const int* in_sizes, int n_in,
                              void* d_out, int out_size, void* d_ws, size_t ws_size,
                              hipStream_t stream) {
    const float* x      = (const float*)d_in[0];
    const int*   edge   = (const int*)d_in[1];
    const float* W1     = (const float*)d_in[2];
    const float* b1     = (const float*)d_in[3];
    const float* W2     = (const float*)d_in[4];
    const float* b2     = (const float*)d_in[5];
    const float* mem1   = (const float*)d_in[6];
    const float* g1_Wih = (const float*)d_in[7];
    const float* g1_bih = (const float*)d_in[9];
    const float* g1_bhh = (const float*)d_in[10];
    const float* wt1_W  = (const float*)d_in[11];
    const float* wt1_b  = (const float*)d_in[12];
    const float* gcn1_b = (const float*)d_in[13];
    const float* mem2   = (const float*)d_in[14];
    const float* g2_Wih = (const float*)d_in[15];
    const float* g2_bih = (const float*)d_in[17];
    const float* g2_bhh = (const float*)d_in[18];
    const float* wt2_W  = (const float*)d_in[19];
    const float* wt2_b  = (const float*)d_in[20];
    const float* gcn2_b = (const float*)d_in[21];
    const float* Wout   = (const float*)d_in[22];
    const float* bout   = (const float*)d_in[23];
    float* out = (float*)d_out;

    const int N = in_sizes[0] / 128;
    const int E = in_sizes[1] / 2;
    const int* row = edge;
    const int* col = edge + E;

    const int NBK = (N + BKS - 1) >> BSH2;   // coarse buckets (391 @ N=100k)
    const int gM  = (N + 63) / 64;           // mlp blocks (64 nodes, 512 thr)
    const int gG  = (N * 64 + 255) / 256;    // gather blocks (wave per node)
    const int gB  = (E + 4095) / 4096;       // bscat blocks

    float* ws    = (float*)d_ws;
    float* bufA  = ws;                        // [N*16] bf16 used (alloc float-sized)
    float* bufB  = bufA + (size_t)N * 16;     // [N*16] bf16 used
    float* dis   = bufB + (size_t)N * 16;     // [N]
    float* sm    = dis + N;                   // smalls
    float* Wn1   = sm;
    float* Wn2   = sm + 256;
    float* wsum  = sm + 512;
    float* bsum  = sm + 528;
    unsigned short* W2bh = (unsigned short*)(sm + 544);   // [16*256] bf16 hi (8 KB)
    unsigned short* W2bl = (unsigned short*)(sm + 2592);  // [16*256] bf16 lo (8 KB)
    unsigned short* W1h = (unsigned short*)(sm + 4640);   // [256*128] bf16 hi
    unsigned short* W1l = (unsigned short*)(sm + 21024);  // [256*128] bf16 lo
    int*   bfill = (int*)(sm + 37408);        // [NBKMAX]
    int*   bbase2= bfill + NBKMAX;            // [NBKMAX+1]
    int*   off   = bbase2 + NBKMAX + 1;       // [N+1]
    int*   srcs  = off + N + 1;               // [E]
    // stage: 16B-aligned int2[NBK*BCAP]
    size_t stoff = (size_t)(srcs + E - (int*)d_ws);
    stoff = (stoff + 3) & ~(size_t)3;
    int2*  stage = (int2*)((int*)d_ws + stoff);

    prep_k<<<1, 256, 0, stream>>>(mem1, g1_Wih, g1_bih, g1_bhh,
                                  mem2, g2_Wih, g2_bih, g2_bhh,
                                  wt1_W, wt1_b, wt2_W, wt2_b,
                                  Wout, bout, W2, Wn1, Wn2, wsum, bsum,
                                  W2bh, W2bl, bfill, NBK);
    wsplit_k<<<128, 256, 0, stream>>>(W1, W1h, W1l);
    bscat_k<<<gB, 256, 0, stream>>>(row, col, bfill, stage, E, NBK);
    cscan_k<<<1, 512, 0, stream>>>(bfill, bbase2, off, NBK, N, E);
    bproc_k<<<NBK, 256, 0, stream>>>(stage, bbase2, off, dis, srcs, N);
    mlp_k<<<gM, 512, 0, stream>>>(x, W1h, W1l, b1, W2bh, W2bl, b2, Wn1, dis,
                                  (unsigned short*)bufA, N);
    gather1_k<<<gG, 256, 0, stream>>>(off, srcs, dis, (unsigned short*)bufA,
                                      gcn1_b, Wn2, (unsigned short*)bufB, N);
    gather2_k<<<gG, 256, 0, stream>>>(off, srcs, dis, (unsigned short*)bufB,
                                      gcn2_b, wsum, bsum, out, N);
}

// Round 5
// 329.573 us; speedup vs baseline: 1.2343x; 1.1219x over previous
//
#include <hip/hip_runtime.h>
#include <math.h>

#define SLOPE 0.01f
#define BKS   256        // dests per bucket (R12: 1024 -> 98 blocks was launch-width-bound)
#define BSH2  8          // log2(BKS)
#define NBKMAX 512       // max coarse buckets (N <= 131072)
#define BCAP  10240      // fixed bucket capacity (mean 8192 + 22 sigma)

typedef short  bf16x8 __attribute__((ext_vector_type(8)));
typedef float  f32x4  __attribute__((ext_vector_type(4)));

__device__ __forceinline__ float lrelu(float v) { return v >= 0.f ? v : SLOPE * v; }

__device__ __forceinline__ unsigned short f2bf(float v) {
    unsigned u = __float_as_uint(v);
    return (unsigned short)((u + 0x7FFFu + ((u >> 16) & 1u)) >> 16);   // RNE
}
__device__ __forceinline__ float bf2f(unsigned short b) {
    return __uint_as_float(((unsigned)b) << 16);
}

// ---------------------------------------------------------------------------
// GRU step (h0=0), regenerate GCN weights, fold Wout/bout, split W2 to bf16
// hi/lo (for MFMA stage2), and init the fixed-capacity bucket cursors.
// ---------------------------------------------------------------------------
__global__ void prep_k(const float* __restrict__ m1, const float* __restrict__ Wih1,
                       const float* __restrict__ bih1, const float* __restrict__ bhh1,
                       const float* __restrict__ m2, const float* __restrict__ Wih2,
                       const float* __restrict__ bih2, const float* __restrict__ bhh2,
                       const float* __restrict__ wtW1, const float* __restrict__ wtb1,
                       const float* __restrict__ wtW2, const float* __restrict__ wtb2,
                       const float* __restrict__ Wout, const float* __restrict__ bout,
                       const float* __restrict__ W2,
                       float* __restrict__ Wn1, float* __restrict__ Wn2,
                       float* __restrict__ wsum, float* __restrict__ bsum,
                       unsigned short* __restrict__ W2bh, unsigned short* __restrict__ W2bl,
                       int* __restrict__ bfill, int NBK) {
    __shared__ float nm[32];   // new_mem1 [0..15], new_mem2 [16..31]
    int t = threadIdx.x;
    if (t < 32) {
        int L = t >> 4, j = t & 15;
        const float* m   = L ? m2   : m1;
        const float* Wih = L ? Wih2 : Wih1;
        const float* bih = L ? bih2 : bih1;
        const float* bhh = L ? bhh2 : bhh1;
        float gr = bih[j], gz = bih[16 + j], gn = bih[32 + j];
        for (int k = 0; k < 16; ++k) {
            float mk = m[k];
            gr += Wih[j * 16 + k] * mk;
            gz += Wih[(16 + j) * 16 + k] * mk;
            gn += Wih[(32 + j) * 16 + k] * mk;
        }
        float r = 1.f / (1.f + expf(-(gr + bhh[j])));
        float z = 1.f / (1.f + expf(-(gz + bhh[16 + j])));
        float n = tanhf(gn + r * bhh[32 + j]);
        nm[t] = (1.f - z) * n;          // + z*h, h==0
    }
    __syncthreads();
    float s1 = wtb1[t], s2 = wtb2[t];
    for (int k = 0; k < 16; ++k) {
        s1 += wtW1[t * 16 + k] * nm[k];
        s2 += wtW2[t * 16 + k] * nm[16 + k];
    }
    Wn1[t] = s1;
    Wn2[t] = s2;
    // W2 [16][256] -> bf16 hi/lo split (row-major, MFMA B-fragment friendly)
    for (int i = t; i < 4096; i += 256) {
        float v = W2[i];
        unsigned short h = f2bf(v);
        W2bh[i] = h;
        W2bl[i] = f2bf(v - bf2f(h));
    }
    if (t < 16) wsum[t] = Wout[t] + Wout[16 + t];
    if (t == 0) bsum[0] = bout[0] + bout[1];
    for (int i = t; i < NBK; i += 256) bfill[i] = i * BCAP;
}

// Split W1 into bf16 hi/lo pair (for split-bf16 MFMA GEMM). 32768 elems.
__global__ void wsplit_k(const float* __restrict__ W1,
                         unsigned short* __restrict__ W1h,
                         unsigned short* __restrict__ W1l) {
    int i = blockIdx.x * 256 + threadIdx.x;
    float v = W1[i];
    unsigned short h = f2bf(v);
    W1h[i] = h;
    W1l[i] = f2bf(v - bf2f(h));
}

// ---------------------------------------------------------------------------
// CSR build: bscat (fixed-base buckets) -> cscan (1 block) -> bproc.
// ---------------------------------------------------------------------------
__global__ void bscat_k(const int* __restrict__ row, const int* __restrict__ col,
                        int* __restrict__ bfill, int2* __restrict__ stage,
                        int E, int NBK) {
    __shared__ int lcnt[NBKMAX];
    __shared__ int lbase[NBKMAX];
    int t = threadIdx.x;
    for (int i = t; i < NBK; i += 256) lcnt[i] = 0;
    __syncthreads();
    int base = blockIdx.x * 4096;
    int r[16], d[16], sl[16];
#pragma unroll
    for (int i = 0; i < 16; ++i) {
        int e = base + i * 256 + t;
        if (e < E) {
            r[i]  = row[e];
            d[i]  = col[e];
            sl[i] = atomicAdd(&lcnt[d[i] >> BSH2], 1);
        } else d[i] = -1;
    }
    __syncthreads();
    for (int i = t; i < NBK; i += 256)
        lbase[i] = lcnt[i] ? atomicAdd(bfill + i, lcnt[i]) : 0;
    __syncthreads();
#pragma unroll
    for (int i = 0; i < 16; ++i) {
        if (d[i] >= 0)
            stage[lbase[d[i] >> BSH2] + sl[i]] = make_int2(r[i], d[i]);
    }
}

// single block: counts from bfill, exclusive scan -> contiguous CSR bases
__global__ __launch_bounds__(512) void cscan_k(const int* __restrict__ bfill,
                                               int* __restrict__ bbase2,
                                               int* __restrict__ off,
                                               int NBK, int N, int E) {
    __shared__ int s[512];
    int t = threadIdx.x;
    int v = (t < NBK) ? (bfill[t] - t * BCAP) : 0;
    s[t] = v;
    __syncthreads();
    for (int d = 1; d < 512; d <<= 1) {
        int u = (t >= d) ? s[t - d] : 0;
        __syncthreads();
        s[t] += u;
        __syncthreads();
    }
    if (t < NBK) bbase2[t] = s[t] - v;
    if (t == 0) { bbase2[NBK] = E; off[N] = E; }
}

// one block per 256-dest bucket: LDS hist (1 counter/thread) -> 256-scan ->
// off/dis -> in-window scatter (~32 KB window, L2-resident). LDS atomics only.
__global__ void bproc_k(const int2* __restrict__ stage, const int* __restrict__ bbase2,
                        int* __restrict__ off, float* __restrict__ dis,
                        int* __restrict__ srcs, int N) {
    __shared__ int lh[BKS];    // counts, then cursors
    __shared__ int ssc[BKS];   // scan
    const int b  = blockIdx.x;
    const int t  = threadIdx.x;
    const int sb = b * BCAP;                     // stage read base
    const int e0 = bbase2[b];
    const int cnt = bbase2[b + 1] - e0;
    lh[t] = 0;
    __syncthreads();
    for (int i = t; i < cnt; i += 256) {
        int2 v = stage[sb + i];
        atomicAdd(&lh[v.y & (BKS - 1)], 1);
    }
    __syncthreads();
    int c = lh[t];
    ssc[t] = c;
    __syncthreads();
    for (int d = 1; d < 256; d <<= 1) {
        int u = (t >= d) ? ssc[t - d] : 0;
        __syncthreads();
        ssc[t] += u;
        __syncthreads();
    }
    int ex = ssc[t] - c;       // exclusive offset within bucket
    {
        int node = b * BKS + t;
        if (node < N) {
            off[node] = e0 + ex;
            dis[node] = rsqrtf((float)(c + 1));   // in-degree + self-loop
        }
    }
    __syncthreads();
    lh[t] = ex;                // cursors
    __syncthreads();
    for (int i = t; i < cnt; i += 256) {
        int2 w = stage[sb + i];
        int pos = e0 + atomicAdd(&lh[w.y & (BKS - 1)], 1);
        srcs[pos] = w.x;
    }
}

// ---------------------------------------------------------------------------
// Fused MLP v8: MLP-depth attack on P1.
//   P1 is nt-outer: all 8 W1 fragment loads (4 ks x hi/lo) issue back-to-back
//   into registers immediately before their MFMA uses (no barrier between, so
//   the scheduler keeps them in flight). Exposed W1 latency per wave drops
//   from ~32 serialized load-pairs to ~2 batched waits.
//   __launch_bounds__(512,4): ~120-VGPR live set needs the 128-reg budget
//   (v7's (512,6) capped at 85 -> compiler serialized at VGPR=40).
// ---------------------------------------------------------------------------
__global__ __launch_bounds__(512, 4) void mlp_k(
        const float* __restrict__ x,
        const unsigned short* __restrict__ W1h,
        const unsigned short* __restrict__ W1l,
        const float* __restrict__ b1,
        const unsigned short* __restrict__ W2bh,
        const unsigned short* __restrict__ W2bl,
        const float* __restrict__ b2,
        const float* __restrict__ Wn1,
        const float* __restrict__ dis,
        unsigned short* __restrict__ xl, int N) {
    __shared__ float sbuf[11008];                    // 44032 B
    unsigned short* xh  = (unsigned short*)sbuf;     // x  [64][136] bf16 hi (17408 B)
    unsigned short* xlo = xh + 8704;                 // x  [64][136] bf16 lo (17408 B)
    unsigned short* h1h = (unsigned short*)sbuf;     // h1 [64][264] bf16 (overlay, 33792 B)
    float*          h2p = sbuf + 8448;               // [2][64][20] f32 partials (10240 B)

    const int t      = threadIdx.x;
    const int nl     = t & 63;
    const int q      = __builtin_amdgcn_readfirstlane(t >> 6);  // wave 0..7
    const int lane15 = t & 15;
    const int quad   = (t & 63) >> 4;
    const int node   = blockIdx.x * 64 + nl;
    const bool valid = node < N;

    // ---- P0: linear-coalesced x load + bf16 hi/lo staging ----
    {
        const float4* x4 = (const float4*)x;
        const size_t tb = (size_t)blockIdx.x * 2048;
        unsigned* xh32 = (unsigned*)xh;
        unsigned* xl32 = (unsigned*)xlo;
#pragma unroll
        for (int kk = 0; kk < 4; ++kk) {
            int idx  = kk * 512 + t;
            int row  = idx >> 5;                 // 0..63
            int col4 = idx & 31;                 // k = 4*col4
            float4 v = make_float4(0.f, 0.f, 0.f, 0.f);
            if (blockIdx.x * 64 + row < N) v = x4[tb + idx];
            unsigned short hx = f2bf(v.x), hy = f2bf(v.y);
            unsigned short hz = f2bf(v.z), hw = f2bf(v.w);
            unsigned short lx = f2bf(v.x - bf2f(hx)), ly = f2bf(v.y - bf2f(hy));
            unsigned short lz = f2bf(v.z - bf2f(hz)), lw = f2bf(v.w - bf2f(hw));
            int base = row * 68 + col4 * 2;      // uint index (row stride 68)
            *(uint2*)(xh32 + base) =
                make_uint2((unsigned)hx | ((unsigned)hy << 16),
                           (unsigned)hz | ((unsigned)hw << 16));
            *(uint2*)(xl32 + base) =
                make_uint2((unsigned)lx | ((unsigned)ly << 16),
                           (unsigned)lz | ((unsigned)lw << 16));
        }
    }
    __syncthreads();

    // ---- P1: GEMM1, wave q owns hu in [q*32, q*32+32); nt-outer, 8-deep
    //          W1 load batch per nt ----
    f32x4 acc[4][2];
#pragma unroll
    for (int mt = 0; mt < 4; ++mt)
#pragma unroll
        for (int nt = 0; nt < 2; ++nt)
            acc[mt][nt] = (f32x4){0.f, 0.f, 0.f, 0.f};

#pragma unroll
    for (int nt = 0; nt < 2; ++nt) {
        bf16x8 bh[4], bl[4];
#pragma unroll
        for (int ks = 0; ks < 4; ++ks) {
            size_t wo = (size_t)(q * 32 + nt * 16 + lane15) * 128 + ks * 32 + quad * 8;
            bh[ks] = *(const bf16x8*)(W1h + wo);
            bl[ks] = *(const bf16x8*)(W1l + wo);
        }
#pragma unroll
        for (int ks = 0; ks < 4; ++ks) {
            const int koff = ks * 32 + quad * 8;
#pragma unroll
            for (int mt = 0; mt < 4; ++mt) {
                bf16x8 ah = *(const bf16x8*)(xh  + (16 * mt + lane15) * 136 + koff);
                bf16x8 al = *(const bf16x8*)(xlo + (16 * mt + lane15) * 136 + koff);
                acc[mt][nt] = __builtin_amdgcn_mfma_f32_16x16x32_bf16(ah, bh[ks], acc[mt][nt], 0, 0, 0);
                acc[mt][nt] = __builtin_amdgcn_mfma_f32_16x16x32_bf16(ah, bl[ks], acc[mt][nt], 0, 0, 0);
                acc[mt][nt] = __builtin_amdgcn_mfma_f32_16x16x32_bf16(al, bh[ks], acc[mt][nt], 0, 0, 0);
            }
        }
    }
    __syncthreads();   // x tile dead; safe to overlay h1

    // ---- P2a: preload W2 B-fragments for this wave's K-half ----
    const int kh  = q >> 2;        // K-half for stage2
    const int mt2 = q & 3;         // m-tile for stage2
    bf16x8 w2hf[4], w2lf[4];
#pragma unroll
    for (int ks2 = 0; ks2 < 4; ++ks2) {
        int wo = lane15 * 256 + (kh * 4 + ks2) * 32 + quad * 8;
        w2hf[ks2] = *(const bf16x8*)(W2bh + wo);
        w2lf[ks2] = *(const bf16x8*)(W2bl + wo);
    }

    // ---- P2b: epilogue GEMM1 -> h1 bf16 (hi only) in LDS ----
#pragma unroll
    for (int nt = 0; nt < 2; ++nt) {
        int hu = q * 32 + nt * 16 + lane15;
        float bb = b1[hu];
#pragma unroll
        for (int mt = 0; mt < 4; ++mt) {
            int row0 = 16 * mt + quad * 4;
#pragma unroll
            for (int r = 0; r < 4; ++r) {
                float v = lrelu(acc[mt][nt][r] + bb);
                h1h[(row0 + r) * 264 + hu] = f2bf(v);
            }
        }
    }
    __syncthreads();

    // ---- P3: GEMM2 partial (wave q: rows 16*mt2.., K-half kh); A bf16,
    //          B split hi/lo (2-term) ----
    f32x4 a2 = (f32x4){0.f, 0.f, 0.f, 0.f};
#pragma unroll
    for (int ks2 = 0; ks2 < 4; ++ks2) {
        const int koff = (kh * 4 + ks2) * 32 + quad * 8;
        bf16x8 ah = *(const bf16x8*)(h1h + (16 * mt2 + lane15) * 264 + koff);
        a2 = __builtin_amdgcn_mfma_f32_16x16x32_bf16(ah, w2hf[ks2], a2, 0, 0, 0);
        a2 = __builtin_amdgcn_mfma_f32_16x16x32_bf16(ah, w2lf[ks2], a2, 0, 0, 0);
    }
    {
        // h2p[kh][row][j], row = 16*mt2 + quad*4 + r, j = lane15, stride 20
        float* dst = h2p + kh * 1280 + (16 * mt2 + quad * 4) * 20 + lane15;
        dst[0] = a2[0]; dst[20] = a2[1]; dst[40] = a2[2]; dst[60] = a2[3];
    }
    __syncthreads();

    // ---- P4: combine partials, b2 + lrelu, Wn1 (16x16), dis scale, store ----
    {
        const f32x4* pa = (const f32x4*)(h2p + nl * 20);
        const f32x4* pb = (const f32x4*)(h2p + 1280 + nl * 20);
        f32x4 s[4];
#pragma unroll
        for (int i = 0; i < 4; ++i) s[i] = pa[i] + pb[i];
        float o0 = 0.f, o1 = 0.f;
        const float* wr0 = Wn1 + (2 * q) * 16;       // uniform -> s_load (one-shot)
        const float* wr1 = Wn1 + (2 * q + 1) * 16;
#pragma unroll
        for (int j = 0; j < 16; ++j) {
            float h = lrelu(s[j >> 2][j & 3] + b2[j]);
            o0 = fmaf(wr0[j], h, o0);
            o1 = fmaf(wr1[j], h, o1);
        }
        if (valid) {
            float d = dis[node];
            unsigned pk = (unsigned)f2bf(d * o0) | ((unsigned)f2bf(d * o1) << 16);
            *(unsigned*)(xl + (size_t)node * 16 + 2 * q) = pk;
        }
    }
}

// ---------------------------------------------------------------------------
// Gather layer 1 v2: one 16-lane group per node (16 nodes/block), 8-deep
// edge batching. 4x fewer & longer waves than wave-per-node; 2x deeper MLP;
// no cross-sub reduce; no redundant projection compute.
// ---------------------------------------------------------------------------
__global__ void gather1_k(const int* __restrict__ off, const int* __restrict__ srcs,
                          const float* __restrict__ dis,
                          const unsigned short* __restrict__ xin,
                          const float* __restrict__ bias, const float* __restrict__ Wn2,
                          unsigned short* __restrict__ xout, int N) {
    __shared__ float w[256];             // transposed: w[j*16+c] = Wn2[c*16+j]
    {
        int j = threadIdx.x >> 4, c = threadIdx.x & 15;
        w[threadIdx.x] = Wn2[c * 16 + j];
    }
    __syncthreads();
    int g = blockIdx.x * 16 + (threadIdx.x >> 4);   // node for this 16-lane group
    int c = threadIdx.x & 15;
    if (g >= N) return;
    float acc = bf2f(xin[(size_t)g * 16 + c]);      // self term
    int e  = off[g];
    int e1 = off[g + 1];
    for (; e + 7 < e1; e += 8) {
        int s0 = srcs[e],     s1 = srcs[e + 1], s2 = srcs[e + 2], s3 = srcs[e + 3];
        int s4 = srcs[e + 4], s5 = srcs[e + 5], s6 = srcs[e + 6], s7 = srcs[e + 7];
        float v0 = bf2f(xin[(size_t)s0 * 16 + c]);
        float v1 = bf2f(xin[(size_t)s1 * 16 + c]);
        float v2 = bf2f(xin[(size_t)s2 * 16 + c]);
        float v3 = bf2f(xin[(size_t)s3 * 16 + c]);
        float v4 = bf2f(xin[(size_t)s4 * 16 + c]);
        float v5 = bf2f(xin[(size_t)s5 * 16 + c]);
        float v6 = bf2f(xin[(size_t)s6 * 16 + c]);
        float v7 = bf2f(xin[(size_t)s7 * 16 + c]);
        acc += ((v0 + v1) + (v2 + v3)) + ((v4 + v5) + (v6 + v7));
    }
    for (; e < e1; ++e)
        acc += bf2f(xin[(size_t)srcs[e] * 16 + c]);
    float d = dis[g];
    float h = lrelu(fmaf(d, acc, bias[c]));
    float o = 0.f;
#pragma unroll
    for (int j = 0; j < 16; ++j) o = fmaf(w[j * 16 + c], __shfl(h, j, 16), o);
    xout[(size_t)g * 16 + c] = f2bf(d * o);
}

// ---------------------------------------------------------------------------
// Gather layer 2 + final projection (16-lane group per node, 8-deep)
// ---------------------------------------------------------------------------
__global__ void gather2_k(const int* __restrict__ off, const int* __restrict__ srcs,
                          const float* __restrict__ dis,
                          const unsigned short* __restrict__ xin,
                          const float* __restrict__ bias, const float* __restrict__ wsum,
                          const float* __restrict__ bsum, float* __restrict__ out, int N) {
    int g = blockIdx.x * 16 + (threadIdx.x >> 4);
    int c = threadIdx.x & 15;
    if (g >= N) return;
    float acc = bf2f(xin[(size_t)g * 16 + c]);
    int e  = off[g];
    int e1 = off[g + 1];
    for (; e + 7 < e1; e += 8) {
        int s0 = srcs[e],     s1 = srcs[e + 1], s2 = srcs[e + 2], s3 = srcs[e + 3];
        int s4 = srcs[e + 4], s5 = srcs[e + 5], s6 = srcs[e + 6], s7 = srcs[e + 7];
        float v0 = bf2f(xin[(size_t)s0 * 16 + c]);
        float v1 = bf2f(xin[(size_t)s1 * 16 + c]);
        float v2 = bf2f(xin[(size_t)s2 * 16 + c]);
        float v3 = bf2f(xin[(size_t)s3 * 16 + c]);
        float v4 = bf2f(xin[(size_t)s4 * 16 + c]);
        float v5 = bf2f(xin[(size_t)s5 * 16 + c]);
        float v6 = bf2f(xin[(size_t)s6 * 16 + c]);
        float v7 = bf2f(xin[(size_t)s7 * 16 + c]);
        acc += ((v0 + v1) + (v2 + v3)) + ((v4 + v5) + (v6 + v7));
    }
    for (; e < e1; ++e)
        acc += bf2f(xin[(size_t)srcs[e] * 16 + c]);
    float v = wsum[c] * lrelu(fmaf(dis[g], acc, bias[c]));
#pragma unroll
    for (int m = 1; m < 16; m <<= 1) v += __shfl_xor(v, m);
    if (c == 0) out[g] = v + bsum[0];
}

// ---------------------------------------------------------------------------
extern "C" void kernel_launch(void* const* d_in, const int* in_sizes, int n_in,
                              void* d_out, int out_size, void* d_ws, size_t ws_size,
                              hipStream_t stream) {
    const float* x      = (const float*)d_in[0];
    const int*   edge   = (const int*)d_in[1];
    const float* W1     = (const float*)d_in[2];
    const float* b1     = (const float*)d_in[3];
    const float* W2     = (const float*)d_in[4];
    const float* b2     = (const float*)d_in[5];
    const float* mem1   = (const float*)d_in[6];
    const float* g1_Wih = (const float*)d_in[7];
    const float* g1_bih = (const float*)d_in[9];
    const float* g1_bhh = (const float*)d_in[10];
    const float* wt1_W  = (const float*)d_in[11];
    const float* wt1_b  = (const float*)d_in[12];
    const float* gcn1_b = (const float*)d_in[13];
    const float* mem2   = (const float*)d_in[14];
    const float* g2_Wih = (const float*)d_in[15];
    const float* g2_bih = (const float*)d_in[17];
    const float* g2_bhh = (const float*)d_in[18];
    const float* wt2_W  = (const float*)d_in[19];
    const float* wt2_b  = (const float*)d_in[20];
    const float* gcn2_b = (const float*)d_in[21];
    const float* Wout   = (const float*)d_in[22];
    const float* bout   = (const float*)d_in[23];
    float* out = (float*)d_out;

    const int N = in_sizes[0] / 128;
    const int E = in_sizes[1] / 2;
    const int* row = edge;
    const int* col = edge + E;

    const int NBK = (N + BKS - 1) >> BSH2;   // coarse buckets (391 @ N=100k)
    const int gM  = (N + 63) / 64;           // mlp blocks (64 nodes, 512 thr)
    const int gG  = (N + 15) / 16;           // gather blocks (16-lane group per node)
    const int gB  = (E + 4095) / 4096;       // bscat blocks

    float* ws    = (float*)d_ws;
    float* bufA  = ws;                        // [N*16] bf16 used (alloc float-sized)
    float* bufB  = bufA + (size_t)N * 16;     // [N*16] bf16 used
    float* dis   = bufB + (size_t)N * 16;     // [N]
    float* sm    = dis + N;                   // smalls
    float* Wn1   = sm;
    float* Wn2   = sm + 256;
    float* wsum  = sm + 512;
    float* bsum  = sm + 528;
    unsigned short* W2bh = (unsigned short*)(sm + 544);   // [16*256] bf16 hi (8 KB)
    unsigned short* W2bl = (unsigned short*)(sm + 2592);  // [16*256] bf16 lo (8 KB)
    unsigned short* W1h = (unsigned short*)(sm + 4640);   // [256*128] bf16 hi
    unsigned short* W1l = (unsigned short*)(sm + 21024);  // [256*128] bf16 lo
    int*   bfill = (int*)(sm + 37408);        // [NBKMAX]
    int*   bbase2= bfill + NBKMAX;            // [NBKMAX+1]
    int*   off   = bbase2 + NBKMAX + 1;       // [N+1]
    int*   srcs  = off + N + 1;               // [E]
    // stage: 16B-aligned int2[NBK*BCAP]
    size_t stoff = (size_t)(srcs + E - (int*)d_ws);
    stoff = (stoff + 3) & ~(size_t)3;
    int2*  stage = (int2*)((int*)d_ws + stoff);

    prep_k<<<1, 256, 0, stream>>>(mem1, g1_Wih, g1_bih, g1_bhh,
                                  mem2, g2_Wih, g2_bih, g2_bhh,
                                  wt1_W, wt1_b, wt2_W, wt2_b,
                                  Wout, bout, W2, Wn1, Wn2, wsum, bsum,
                                  W2bh, W2bl, bfill, NBK);
    wsplit_k<<<128, 256, 0, stream>>>(W1, W1h, W1l);
    bscat_k<<<gB, 256, 0, stream>>>(row, col, bfill, stage, E, NBK);
    cscan_k<<<1, 512, 0, stream>>>(bfill, bbase2, off, NBK, N, E);
    bproc_k<<<NBK, 256, 0, stream>>>(stage, bbase2, off, dis, srcs, N);
    mlp_k<<<gM, 512, 0, stream>>>(x, W1h, W1l, b1, W2bh, W2bl, b2, Wn1, dis,
                                  (unsigned short*)bufA, N);
    gather1_k<<<gG, 256, 0, stream>>>(off, srcs, dis, (unsigned short*)bufA,
                                      gcn1_b, Wn2, (unsigned short*)bufB, N);
    gather2_k<<<gG, 256, 0, stream>>>(off, srcs, dis, (unsigned short*)bufB,
                                      gcn2_b, wsum, bsum, out, N);
}